// Round 11
// baseline (149.629 us; speedup 1.0000x reference)
//
#include <hip/hip_runtime.h>
#include <hip/hip_bf16.h>

// Problem constants
#define BQ    2
#define LQ    2048
#define DMQ   1024
#define HQ    4
#define DHQ   128
#define TOTQ  512
#define BLQ   4096      // B*L
#define NPROJ 2816      // padded concat: Wq(512) Wk(512) Wv(1024) Wg(512) Wa(4) Wb(4) pad(248) -> 11x256
#define KPROJ 1024
#define CT    64        // scan chunk length
#define NCH   32        // chunks (LQ/CT)

typedef short bf16x8 __attribute__((ext_vector_type(8)));
typedef short s16x4  __attribute__((ext_vector_type(4)));
typedef float f32x4  __attribute__((ext_vector_type(4)));

#define MFMA16(a, b, c) __builtin_amdgcn_mfma_f32_16x16x32_bf16(a, b, c, 0, 0, 0)

__device__ __forceinline__ float siluf(float x) { return x / (1.f + __expf(-x)); }
__device__ __forceinline__ float sigf(float x)  { return 1.f / (1.f + __expf(-x)); }
__device__ __forceinline__ short bf16s(float x) {
  return __builtin_bit_cast(short, __float2bfloat16(x));
}
__device__ __forceinline__ float bfu2f(unsigned short u) {
  return __bfloat162float(__builtin_bit_cast(__hip_bfloat16, u));
}
__device__ __forceinline__ bf16x8 pack8(f32x4 a, f32x4 b) {
  bf16x8 r;
  r[0] = bf16s(a.x); r[1] = bf16s(a.y); r[2] = bf16s(a.z); r[3] = bf16s(a.w);
  r[4] = bf16s(b.x); r[5] = bf16s(b.y); r[6] = bf16s(b.z); r[7] = bf16s(b.w);
  return r;
}

// global -> LDS direct load, 16B per lane. LDS dest must be wave-uniform base;
// HW writes base + lane*16.
__device__ __forceinline__ void gload_lds16(const void* g, void* l) {
  __builtin_amdgcn_global_load_lds(
      (__attribute__((address_space(1))) void*)(unsigned long long)g,
      (__attribute__((address_space(3))) void*)(unsigned int)(unsigned long long)l,
      16, 0, 0);
}

// ---------------- merged casts: x->XB, Wo->WOB, Wcat (one launch) ----------------
__global__ __launch_bounds__(256)
void cast_all_kernel(const float* __restrict__ x, const float* __restrict__ Wo,
                     const float* __restrict__ Wq, const float* __restrict__ Wk,
                     const float* __restrict__ Wv, const float* __restrict__ Wg,
                     const float* __restrict__ Wa, const float* __restrict__ Wb,
                     __hip_bfloat16* __restrict__ XB, __hip_bfloat16* __restrict__ WOB,
                     __hip_bfloat16* __restrict__ Wcat)
{
  const int bid = blockIdx.x;
  const int tid = threadIdx.x;
  if (bid < 4096) {                      // x: 4096x1024 f32, 4/thread
    const int i = bid * 256 + tid;
    float4 v = ((const float4*)x)[i];
    __hip_bfloat16 o[4] = { __float2bfloat16(v.x), __float2bfloat16(v.y),
                            __float2bfloat16(v.z), __float2bfloat16(v.w) };
    *(ushort4*)((unsigned short*)XB + (size_t)i * 4) = *(ushort4*)o;
  } else if (bid < 4608) {               // Wo: 1024x512 f32
    const int i = (bid - 4096) * 256 + tid;
    float4 v = ((const float4*)Wo)[i];
    __hip_bfloat16 o[4] = { __float2bfloat16(v.x), __float2bfloat16(v.y),
                            __float2bfloat16(v.z), __float2bfloat16(v.w) };
    *(ushort4*)((unsigned short*)WOB + (size_t)i * 4) = *(ushort4*)o;
  } else {                               // Wcat: 2816 rows x 1024
    const int i4 = (bid - 4608) * 256 + tid;
    const int row = i4 >> 8;
    const int col = (i4 & 255) * 4;
    const int idx = row * 1024 + col;
    float4 v;
    if      (row < 512)  v = *(const float4*)(Wq + idx);
    else if (row < 1024) v = *(const float4*)(Wk + idx - 512 * 1024);
    else if (row < 2048) v = *(const float4*)(Wv + idx - 1024 * 1024);
    else if (row < 2560) v = *(const float4*)(Wg + idx - 2048 * 1024);
    else if (row < 2564) v = *(const float4*)(Wa + (row - 2560) * 1024 + col);
    else if (row < 2568) v = *(const float4*)(Wb + (row - 2564) * 1024 + col);
    else                 v = make_float4(0.f, 0.f, 0.f, 0.f);
    __hip_bfloat16 o[4] = { __float2bfloat16(v.x), __float2bfloat16(v.y),
                            __float2bfloat16(v.z), __float2bfloat16(v.w) };
    *(ushort4*)((unsigned short*)Wcat + idx) = *(ushort4*)o;
  }
}

// ---------------- bf16 MFMA GEMM: C(TOUT, MxN) = A(M,K) * B(N,K)^T ----------------
// 128x256 tile, 8 waves (512 thr), 2-phase double-buffered LDS, 1D grid with
// XCD-chunked swizzle (consecutive swizzled ids share the B-panel -> L2-hot).
// M tiles fixed at 32 (M=4096). TOUT = bf16 (proj) or f32 (final).
// If aux != nullptr, output columns [auxc0, auxc0+8) are ALSO stored f32 to
// aux[row*8 + (col-auxc0)] (keeps alpha/beta logits full-precision).
template <typename TOUT>
__global__ __launch_bounds__(512)
void gemm_bt_kernel(const __hip_bfloat16* __restrict__ A,
                    const __hip_bfloat16* __restrict__ Bw,
                    TOUT* __restrict__ C, int M, int N, int K,
                    float* __restrict__ aux, int auxc0)
{
  __shared__ __hip_bfloat16 As[2 * 128 * 32];   // 16 KB
  __shared__ __hip_bfloat16 Bs[2 * 256 * 32];   // 32 KB
  const int tid  = threadIdx.x;
  const int lane = tid & 63;
  const int w    = tid >> 6;            // 0..7
  const int wm   = w >> 2, wn = w & 3;  // 2 x 4 wave grid, 64x64 per wave
  const int nwg  = gridDim.x;
  const int bid  = blockIdx.x;
  const int wgid = (bid & 7) * (nwg >> 3) + (bid >> 3);   // XCD-chunked (nwg%8==0)
  const int tm   = wgid & 31;           // 32 M-tiles of 128
  const int tn   = wgid >> 5;           // N-tiles of 256
  const int lr   = lane & 15, lk = lane >> 4;

  f32x4 acc[4][4] = {};

  const int srow = tid >> 2;            // 0..127
  const int scol = (tid & 3) * 8;
  const __hip_bfloat16* Ap = A  + (size_t)(tm * 128 + srow) * K + scol;
  const __hip_bfloat16* Bp = Bw + (size_t)(tn * 256 + srow) * K + scol;
  const size_t halfB = (size_t)128 * K;
  char* AsB  = (char*)As;
  char* BsB  = (char*)Bs;
  const int nk = K >> 5;

  // prologue: stage K-tile 0 into buffer 0
  {
    gload_lds16(Ap,         AsB + w * 1024);
    gload_lds16(Bp,         BsB + w * 1024);
    gload_lds16(Bp + halfB, BsB + 8192 + w * 1024);
  }
  __syncthreads();

  for (int it = 0; it < nk; ++it) {
    const int sel = it & 1;
    // prefetch next K-tile into the other buffer (no wait here)
    if (it + 1 < nk) {
      const int kk = (it + 1) * 32;
      gload_lds16(Ap + kk,         AsB + ((sel ^ 1) * 8192)  + w * 1024);
      gload_lds16(Bp + kk,         BsB + ((sel ^ 1) * 16384) + w * 1024);
      gload_lds16(Bp + halfB + kk, BsB + ((sel ^ 1) * 16384) + 8192 + w * 1024);
    }
    // compute on current buffer
    const char* AsR = AsB + sel * 8192;
    const char* BsR = BsB + sel * 16384;
    bf16x8 af[4], bfv[4];
#pragma unroll
    for (int m = 0; m < 4; ++m)
      af[m]  = *(const bf16x8*)(AsR + ((wm * 64 + m * 16 + lr) * 32 + lk * 8) * 2);
#pragma unroll
    for (int n = 0; n < 4; ++n)
      bfv[n] = *(const bf16x8*)(BsR + ((wn * 64 + n * 16 + lr) * 32 + lk * 8) * 2);
#pragma unroll
    for (int m = 0; m < 4; ++m)
#pragma unroll
      for (int n = 0; n < 4; ++n)
        acc[m][n] = MFMA16(af[m], bfv[n], acc[m][n]);
    // barrier (drains vmcnt): next tile resident, current buffer reusable
    __syncthreads();
  }

  const int crow0 = tm * 128 + wm * 64 + lk * 4;
  const int ccol0 = tn * 256 + wn * 64 + lr;
#pragma unroll
  for (int m = 0; m < 4; ++m)
#pragma unroll
    for (int n = 0; n < 4; ++n) {
      const int cc = ccol0 + n * 16;
#pragma unroll
      for (int j = 0; j < 4; ++j) {
        const float v = acc[m][n][j];
        const size_t row = (size_t)(crow0 + m * 16 + j);
        if constexpr (sizeof(TOUT) == 2)
          ((unsigned short*)C)[row * N + cc] = (unsigned short)bf16s(v);
        else
          C[row * N + cc] = v;
        if (aux && cc >= auxc0 && cc < auxc0 + 8)
          aux[row * 8 + (cc - auxc0)] = v;
      }
    }
}

// ---------------- conv(4-tap causal) + silu + l2norm + sigmoid(a,b) ----------------
// Sliding-window over 8 timesteps per block (512 blocks). CBUF is bf16;
// alpha/beta logits come from the f32 side buffer abf. Outputs bf16.
__global__ __launch_bounds__(256)
void conv_act_kernel(const __hip_bfloat16* __restrict__ C, const float* __restrict__ abf,
                     const float* __restrict__ qcw, const float* __restrict__ qcb,
                     const float* __restrict__ kcw, const float* __restrict__ kcb,
                     const float* __restrict__ vcw, const float* __restrict__ vcb,
                     __hip_bfloat16* __restrict__ qh, __hip_bfloat16* __restrict__ kh,
                     __hip_bfloat16* __restrict__ vm, __hip_bfloat16* __restrict__ vg,
                     float* __restrict__ al, float* __restrict__ be)
{
  const int blk = blockIdx.x;           // 512
  const int bl0 = blk * 8;              // global row start (never crosses b: 2048%8==0)
  const int t0  = bl0 & (LQ - 1);       // local t start
  const int tid = threadIdx.x;
  const unsigned short* Cu = (const unsigned short*)C;
  __shared__ float red[4][16];

  float2 qv[8], kv[8];
  float sq[8], sk[8];
#pragma unroll
  for (int t = 0; t < 8; ++t) { sq[t] = 0.f; sk[t] = 0.f; }

  {
    const int c0 = tid * 2;
    const float4 wqA = *(const float4*)(qcw + 4 * c0);
    const float4 wqB = *(const float4*)(qcw + 4 * c0 + 4);
    const float4 wkA = *(const float4*)(kcw + 4 * c0);
    const float4 wkB = *(const float4*)(kcw + 4 * c0 + 4);
    const float2 bq = *(const float2*)(qcb + c0);
    const float2 bk = *(const float2*)(kcb + c0);
    float2 wrq[11], wrk[11];
#pragma unroll
    for (int r = 0; r < 11; ++r) {
      const int tt = t0 - 3 + r;
      if (tt >= 0) {
        const unsigned short* Cr = Cu + (size_t)(bl0 - 3 + r) * NPROJ;
        const ushort2 aq = *(const ushort2*)(Cr + c0);
        const ushort2 ak = *(const ushort2*)(Cr + 512 + c0);
        wrq[r] = make_float2(bfu2f(aq.x), bfu2f(aq.y));
        wrk[r] = make_float2(bfu2f(ak.x), bfu2f(ak.y));
      } else {
        wrq[r] = make_float2(0.f, 0.f);
        wrk[r] = make_float2(0.f, 0.f);
      }
    }
#pragma unroll
    for (int t = 0; t < 8; ++t) {
      float aq0 = bq.x, aq1 = bq.y, ak0 = bk.x, ak1 = bk.y;
#pragma unroll
      for (int j = 0; j < 4; ++j) {
        aq0 = fmaf(((const float*)&wqA)[j], wrq[t + j].x, aq0);
        aq1 = fmaf(((const float*)&wqB)[j], wrq[t + j].y, aq1);
        ak0 = fmaf(((const float*)&wkA)[j], wrk[t + j].x, ak0);
        ak1 = fmaf(((const float*)&wkB)[j], wrk[t + j].y, ak1);
      }
      const float q0 = siluf(aq0), q1 = siluf(aq1);
      const float k0 = siluf(ak0), k1 = siluf(ak1);
      qv[t] = make_float2(q0, q1);
      kv[t] = make_float2(k0, k1);
      sq[t] = fmaf(q1, q1, fmaf(q0, q0, sq[t]));
      sk[t] = fmaf(k1, k1, fmaf(k0, k0, sk[t]));
    }
  }
  // reduce sq,sk across 64 lanes, then across 4 waves
#pragma unroll
  for (int m = 1; m < 64; m <<= 1) {
#pragma unroll
    for (int t = 0; t < 8; ++t) {
      sq[t] += __shfl_xor(sq[t], m);
      sk[t] += __shfl_xor(sk[t], m);
    }
  }
  {
    const int w = tid >> 6, lane = tid & 63;
    if (lane == 0) {
#pragma unroll
      for (int t = 0; t < 8; ++t) { red[w][t] = sq[t]; red[w][8 + t] = sk[t]; }
    }
  }
  __syncthreads();
  float rnq[8], rnk[8];
#pragma unroll
  for (int t = 0; t < 8; ++t) {
    const float SQ = red[0][t] + red[1][t] + red[2][t] + red[3][t];
    const float SK = red[0][8 + t] + red[1][8 + t] + red[2][8 + t] + red[3][8 + t];
    rnq[t] = 1.f / fmaxf(sqrtf(SQ), 1e-12f);
    rnk[t] = 1.f / fmaxf(sqrtf(SK), 1e-12f);
  }
  {
    const int c0 = tid * 2;
#pragma unroll
    for (int t = 0; t < 8; ++t) {
      ushort2 oq, ok;
      oq.x = (unsigned short)bf16s(qv[t].x * rnq[t]);
      oq.y = (unsigned short)bf16s(qv[t].y * rnq[t]);
      ok.x = (unsigned short)bf16s(kv[t].x * rnk[t]);
      ok.y = (unsigned short)bf16s(kv[t].y * rnk[t]);
      *(ushort2*)((unsigned short*)qh + (size_t)(bl0 + t) * 512 + c0) = oq;
      *(ushort2*)((unsigned short*)kh + (size_t)(bl0 + t) * 512 + c0) = ok;
    }
  }
  // v: 4 consecutive channels per thread
  {
    const int cv = tid * 4;   // 0..1023
    const float4 wv0 = *(const float4*)(vcw + 4 * cv);
    const float4 wv1 = *(const float4*)(vcw + 4 * cv + 4);
    const float4 wv2 = *(const float4*)(vcw + 4 * cv + 8);
    const float4 wv3 = *(const float4*)(vcw + 4 * cv + 12);
    const float4 bv4 = *(const float4*)(vcb + cv);
    float4 wr[11];
#pragma unroll
    for (int r = 0; r < 11; ++r) {
      const int tt = t0 - 3 + r;
      if (tt >= 0) {
        const ushort4 u = *(const ushort4*)(Cu + (size_t)(bl0 - 3 + r) * NPROJ + 1024 + cv);
        wr[r] = make_float4(bfu2f(u.x), bfu2f(u.y), bfu2f(u.z), bfu2f(u.w));
      } else {
        wr[r] = make_float4(0.f, 0.f, 0.f, 0.f);
      }
    }
#pragma unroll
    for (int t = 0; t < 8; ++t) {
      float a0 = bv4.x, a1 = bv4.y, a2 = bv4.z, a3 = bv4.w;
#pragma unroll
      for (int j = 0; j < 4; ++j) {
        a0 = fmaf(((const float*)&wv0)[j], ((const float*)&wr[t + j])[0], a0);
        a1 = fmaf(((const float*)&wv1)[j], ((const float*)&wr[t + j])[1], a1);
        a2 = fmaf(((const float*)&wv2)[j], ((const float*)&wr[t + j])[2], a2);
        a3 = fmaf(((const float*)&wv3)[j], ((const float*)&wr[t + j])[3], a3);
      }
      ushort4 o;
      o.x = (unsigned short)bf16s(siluf(a0));
      o.y = (unsigned short)bf16s(siluf(a1));
      o.z = (unsigned short)bf16s(siluf(a2));
      o.w = (unsigned short)bf16s(siluf(a3));
      if (cv < 512) *(ushort4*)((unsigned short*)vm + (size_t)(bl0 + t) * 512 + cv)         = o;
      else          *(ushort4*)((unsigned short*)vg + (size_t)(bl0 + t) * 512 + (cv - 512)) = o;
    }
  }
  // alpha/beta from f32 side buffer: threads 0..63 cover 8 t x (4 al + 4 be)
  if (tid < 64) {
    const int t = tid >> 3;
    const int k = tid & 7;
    const float v = abf[(size_t)(bl0 + t) * 8 + k];
    if (k < 4) al[(size_t)(bl0 + t) * 4 + k]       = sigf(v);
    else       be[(size_t)(bl0 + t) * 4 + (k - 4)] = sigf(v);
  }
}

// ---------------- scan phase A (FUSED with transition), 512 threads ----------------
// 256 blocks = 32 chunks x 8 (b,h); 8 waves (2 waves/SIMD).
// Work split: G/Pq MFMA over 8 waves (t-band x s-half); substitution with TWO
// threads per column (A: rows 0-7 of each 16-block, B: rows 8-15, barrier
// handoff through the Xl spill); transition over 8 waves (row-band x col-qtr).
__global__ __launch_bounds__(512)
void scan_phaseA_kernel(const __hip_bfloat16* __restrict__ qh, const __hip_bfloat16* __restrict__ kh,
                        const __hip_bfloat16* __restrict__ vm, const float* __restrict__ al,
                        const float* __restrict__ be,
                        short* __restrict__ WTB, short* __restrict__ ZB,
                        short* __restrict__ PHB, float* __restrict__ GV,
                        short* __restrict__ TRB, float* __restrict__ BF)
{
  __shared__ char sm[136192];
  float* Xl = (float*)(sm);                             // [64][256] f32 (aliases KBl/QBl)
  __hip_bfloat16* KBl = (__hip_bfloat16*)(sm);          // [64][136]
  __hip_bfloat16* QBl = (__hip_bfloat16*)(sm + 17408);  // [64][136]
  float* Ll  = (float*)(sm + 65536);                    // [64][68]
  float* dv  = (float*)(sm + 82944);                    // [64]
  float* bv  = (float*)(sm + 83200);                    // [64]
  float* gbv = (float*)(sm + 83456);                    // [64]
  float* fvs = (float*)(sm + 83712);                    // [64]
  short* KTl  = (short*)(sm + 83968);                   // [128][68] bf16
  short* WTFl = (short*)(sm + 101376);                  // [128][68] bf16
  short* ZFl  = (short*)(sm + 118784);                  // [128][68] bf16

  const int cb = blockIdx.x;
  const int bh = cb & 7, c = cb >> 3;
  const int b = bh >> 2, h = bh & 3;
  const int tid = threadIdx.x;          // 0..511
  const int lane = tid & 63;
  const int w = tid >> 6;               // 0..7
  const int lr = lane & 15, lk = lane >> 4;
  const size_t rowbase = (size_t)(b * LQ + c * CT) * 512 + h * 128;

  // stage K,Q -> LDS bf16 (padded rows of 136); 2 reps of 512 threads
#pragma unroll
  for (int rep = 0; rep < 2; ++rep) {
    const int fid = tid + rep * 512;       // 0..1023
    const int r = fid >> 4;
    const int cg = (fid & 15) * 8;
    *(bf16x8*)(KBl + r * 136 + cg) = *(const bf16x8*)(kh + rowbase + (size_t)r * 512 + cg);
    *(bf16x8*)(QBl + r * 136 + cg) = *(const bf16x8*)(qh + rowbase + (size_t)r * 512 + cg);
  }
  // decay prefix (wave 0)
  if (w == 0) {
    float la = __logf(al[(size_t)(b * LQ + c * CT + lane) * 4 + h]);
    const float bb = be[(size_t)(b * LQ + c * CT + lane) * 4 + h];
#pragma unroll
    for (int off = 1; off < 64; off <<= 1) {
      const float tv = __shfl_up(la, off, 64);
      if (lane >= off) la += tv;
    }
    dv[lane] = la; bv[lane] = bb; gbv[lane] = bb * __expf(la);
    const float d63 = __shfl(la, 63, 64);
    fvs[lane] = __expf(d63 - la);
    GV[cb * 64 + lane] = __expf(la);
  }
  __syncthreads();

  // G = K K^T, Pq = Q K^T : wave w owns t-band (w&3) and s-half (w>>2)
  {
    const int tb = (w & 3) * 16;
    const int sh = (w >> 2) * 2;          // s-tile base (2 tiles per wave)
    f32x4 aG[2] = {}, aP[2] = {};
#pragma unroll
    for (int ks = 0; ks < 4; ++ks) {
      bf16x8 bk[2];
#pragma unroll
      for (int nt = 0; nt < 2; ++nt)
        bk[nt] = *(const bf16x8*)(KBl + ((sh + nt) * 16 + lr) * 136 + ks * 32 + lk * 8);
      const bf16x8 ak = *(const bf16x8*)(KBl + (tb + lr) * 136 + ks * 32 + lk * 8);
      const bf16x8 aq = *(const bf16x8*)(QBl + (tb + lr) * 136 + ks * 32 + lk * 8);
#pragma unroll
      for (int nt = 0; nt < 2; ++nt) {
        aG[nt] = MFMA16(ak, bk[nt], aG[nt]);
        aP[nt] = MFMA16(aq, bk[nt], aP[nt]);
      }
    }
#pragma unroll
    for (int nt = 0; nt < 2; ++nt)
#pragma unroll
      for (int jj = 0; jj < 4; ++jj) {
        const int t = tb + lk * 4 + jj;
        const int s = (sh + nt) * 16 + lr;
        const float eg = __expf(dv[t] - dv[s]);
        Ll[t * 68 + s] = (t > s) ? bv[t] * eg * aG[nt][jj] : 0.f;
        PHB[(size_t)cb * 4096 + t * 64 + s] = (s <= t) ? bf16s(eg * aP[nt][jj]) : (short)0;
      }
  }
  // KT (LDS) = K^T from staged KBl, BEFORE Xl overwrites it
  if (tid < 128) {
    const short* Kbs = (const short*)KBl;
#pragma unroll
    for (int s4 = 0; s4 < 16; ++s4) {
      s16x4 pk;
#pragma unroll
      for (int e = 0; e < 4; ++e)
        pk[e] = Kbs[(s4 * 4 + e) * 136 + tid];
      *(s16x4*)(KTl + tid * 68 + s4 * 4) = pk;
    }
  }
  __syncthreads();   // KBl/QBl dead from here -> Xl may overwrite

  // ---- blocked forward substitution: 2 threads per column ----
  const int j = tid & 255;
  const int half = tid >> 8;
  const int i0 = half * 8;
  const __hip_bfloat16* src = (j < 128) ? kh : vm;
  const __hip_bfloat16* xp = src + rowbase + (j & 127);
  float* XlC = Xl + j;                 // private column, stride 256 floats
  short* dstN = (j < 128) ? (WTB + (size_t)cb * 8192 + j)
                          : (ZB  + (size_t)cb * 8192 + (j - 128));
  short* dstT = (j < 128) ? (WTFl + j * 68)
                          : (ZFl  + (j - 128) * 68);

  for (int r = 0; r < 4; ++r) {
    float u[8];
#pragma unroll
    for (int i = 0; i < 8; ++i) {
      const int t = r * 16 + i0 + i;
      u[i] = __bfloat162float(xp[(size_t)t * 512]) * ((j < 128) ? gbv[t] : bv[t]);
    }
    for (int sc = 0; sc < r; ++sc) {
      float xs[16];
#pragma unroll
      for (int k = 0; k < 16; ++k) xs[k] = XlC[(sc * 16 + k) * 256];
#pragma unroll
      for (int i = 0; i < 8; ++i) {
        const float* lrow = Ll + (r * 16 + i0 + i) * 68 + sc * 16;
        const f32x4 l0 = *(const f32x4*)(lrow);
        const f32x4 l1 = *(const f32x4*)(lrow + 4);
        const f32x4 l2 = *(const f32x4*)(lrow + 8);
        const f32x4 l3 = *(const f32x4*)(lrow + 12);
        f32x4 acc = {};
        acc.x = fmaf(l0.x, xs[0],  acc.x); acc.y = fmaf(l0.y, xs[1],  acc.y);
        acc.z = fmaf(l0.z, xs[2],  acc.z); acc.w = fmaf(l0.w, xs[3],  acc.w);
        acc.x = fmaf(l1.x, xs[4],  acc.x); acc.y = fmaf(l1.y, xs[5],  acc.y);
        acc.z = fmaf(l1.z, xs[6],  acc.z); acc.w = fmaf(l1.w, xs[7],  acc.w);
        acc.x = fmaf(l2.x, xs[8],  acc.x); acc.y = fmaf(l2.y, xs[9],  acc.y);
        acc.z = fmaf(l2.z, xs[10], acc.z); acc.w = fmaf(l2.w, xs[11], acc.w);
        acc.x = fmaf(l3.x, xs[12], acc.x); acc.y = fmaf(l3.y, xs[13], acc.y);
        acc.z = fmaf(l3.z, xs[14], acc.z); acc.w = fmaf(l3.w, xs[15], acc.w);
        u[i] -= (acc.x + acc.y) + (acc.z + acc.w);
      }
    }
    if (half == 0) {
#pragma unroll
      for (int i = 1; i < 8; ++i) {
        const float* lrow = Ll + (r * 16 + i) * 68 + r * 16;
        f32x4 acc = {};
#pragma unroll
        for (int k4 = 0; k4 < 2; ++k4) {
          if (k4 * 4 < i) {
            const f32x4 lv = *(const f32x4*)(lrow + k4 * 4);
            acc.x = fmaf(lv.x, u[k4 * 4 + 0], acc.x);
            acc.y = fmaf(lv.y, u[k4 * 4 + 1], acc.y);
            acc.z = fmaf(lv.z, u[k4 * 4 + 2], acc.z);
            acc.w = fmaf(lv.w, u[k4 * 4 + 3], acc.w);
          }
        }
        u[i] -= (acc.x + acc.y) + (acc.z + acc.w);
      }
#pragma unroll
      for (int i = 0; i < 8; ++i) XlC[(r * 16 + i) * 256] = u[i];
#pragma unroll
      for (int i = 0; i < 8; ++i) dstN[(r * 16 + i) * 128] = bf16s(u[i]);
#pragma unroll
      for (int s4 = 0; s4 < 2; ++s4) {
        s16x4 p;
#pragma unroll
        for (int e = 0; e < 4; ++e)
          p[e] = bf16s(fvs[r * 16 + s4 * 4 + e] * u[s4 * 4 + e]);
        *(s16x4*)(dstT + r * 16 + s4 * 4) = p;
      }
    }
    __syncthreads();   // A-half spill visible
    if (half == 1) {
      float xa[8];
#pragma unroll
      for (int k = 0; k < 8; ++k) xa[k] = XlC[(r * 16 + k) * 256];
#pragma unroll
      for (int i = 0; i < 8; ++i) {
        const float* lrow = Ll + (r * 16 + 8 + i) * 68 + r * 16;
        const f32x4 l0 = *(const f32x4*)(lrow);
        const f32x4 l1 = *(const f32x4*)(lrow + 4);
        f32x4 acc = {};
        acc.x = fmaf(l0.x, xa[0], acc.x); acc.y = fmaf(l0.y, xa[1], acc.y);
        acc.z = fmaf(l0.z, xa[2], acc.z); acc.w = fmaf(l0.w, xa[3], acc.w);
        acc.x = fmaf(l1.x, xa[4], acc.x); acc.y = fmaf(l1.y, xa[5], acc.y);
        acc.z = fmaf(l1.z, xa[6], acc.z); acc.w = fmaf(l1.w, xa[7], acc.w);
        u[i] -= (acc.x + acc.y) + (acc.z + acc.w);
      }
#pragma unroll
      for (int i = 1; i < 8; ++i) {
        const float* lrow = Ll + (r * 16 + 8 + i) * 68 + r * 16 + 8;
        f32x4 acc = {};
#pragma unroll
        for (int k4 = 0; k4 < 2; ++k4) {
          if (k4 * 4 < i) {
            const f32x4 lv = *(const f32x4*)(lrow + k4 * 4);
            acc.x = fmaf(lv.x, u[k4 * 4 + 0], acc.x);
            acc.y = fmaf(lv.y, u[k4 * 4 + 1], acc.y);
            acc.z = fmaf(lv.z, u[k4 * 4 + 2], acc.z);
            acc.w = fmaf(lv.w, u[k4 * 4 + 3], acc.w);
          }
        }
        u[i] -= (acc.x + acc.y) + (acc.z + acc.w);
      }
#pragma unroll
      for (int i = 0; i < 8; ++i) XlC[(r * 16 + 8 + i) * 256] = u[i];
#pragma unroll
      for (int i = 0; i < 8; ++i) dstN[(r * 16 + 8 + i) * 128] = bf16s(u[i]);
#pragma unroll
      for (int s4 = 0; s4 < 2; ++s4) {
        s16x4 p;
#pragma unroll
        for (int e = 0; e < 4; ++e)
          p[e] = bf16s(fvs[r * 16 + 8 + s4 * 4 + e] * u[s4 * 4 + e]);
        *(s16x4*)(dstT + r * 16 + 8 + s4 * 4) = p;
      }
    }
    __syncthreads();   // block r fully solved
  }

  // ---- fused transition: 8 waves, wave w owns row-band (w&3) x col-quarter (w>>2)
  const float gc = __expf(dv[63]);
  const int rb = (w & 3) * 32;
  const int cq = (w >> 2) * 4;
  {
    f32x4 acc[2][4] = {};
#pragma unroll
    for (int ks = 0; ks < 2; ++ks) {
      const bf16x8 a0 = *(const bf16x8*)(KTl + (rb + lr) * 68 + ks * 32 + lk * 8);
      const bf16x8 a1 = *(const bf16x8*)(KTl + (rb + 16 + lr) * 68 + ks * 32 + lk * 8);
#pragma unroll
      for (int nt = 0; nt < 4; ++nt) {
        const bf16x8 bm = *(const bf16x8*)(WTFl + ((cq + nt) * 16 + lr) * 68 + ks * 32 + lk * 8);
        acc[0][nt] = MFMA16(a0, bm, acc[0][nt]);
        acc[1][nt] = MFMA16(a1, bm, acc[1][nt]);
      }
    }
#pragma unroll
    for (int mt = 0; mt < 2; ++mt)
#pragma unroll
      for (int nt = 0; nt < 4; ++nt)
#pragma unroll
        for (int jj = 0; jj < 4; ++jj) {
          const int jr = rb + mt * 16 + lk * 4 + jj;
          const int m  = (cq + nt) * 16 + lr;
          const float v = ((jr == m) ? gc : 0.f) - acc[mt][nt][jj];
          TRB[(size_t)cb * 16384 + jr * 128 + m] = bf16s(v);
        }
  }
  {
    f32x4 acc[2][4] = {};
#pragma unroll
    for (int ks = 0; ks < 2; ++ks) {
      const bf16x8 a0 = *(const bf16x8*)(ZFl + (rb + lr) * 68 + ks * 32 + lk * 8);
      const bf16x8 a1 = *(const bf16x8*)(ZFl + (rb + 16 + lr) * 68 + ks * 32 + lk * 8);
#pragma unroll
      for (int nt = 0; nt < 4; ++nt) {
        const bf16x8 bj = *(const bf16x8*)(KTl + ((cq + nt) * 16 + lr) * 68 + ks * 32 + lk * 8);
        acc[0][nt] = MFMA16(a0, bj, acc[0][nt]);
        acc[1][nt] = MFMA16(a1, bj, acc[1][nt]);
      }
    }
#pragma unroll
    for (int mt = 0; mt < 2; ++mt)
#pragma unroll
      for (int nt = 0; nt < 4; ++nt)
#pragma unroll
        for (int jj = 0; jj < 4; ++jj) {
          const int ir = rb + mt * 16 + lk * 4 + jj;
          const int jc = (cq + nt) * 16 + lr;
          BF[(size_t)cb * 16384 + ir * 128 + jc] = acc[mt][nt][jj];
        }
  }
}

// ---------------- scan state: serial chunk recurrence, S rows independent ----
#define L2_PREFETCH(BT, BA, CC) do {                                               \
  const int cbn_ = (CC) * 8 + bh;                                                  \
  _Pragma("unroll") for (int nt = 0; nt < 2; ++nt) {                               \
    _Pragma("unroll") for (int ks = 0; ks < 4; ++ks)                               \
      BT[nt][ks] = *(const bf16x8*)(TRB + (size_t)cbn_ * 16384 +                   \
                                    (w * 32 + nt * 16 + lr) * 128 + ks * 32 + lk * 8); \
    _Pragma("unroll") for (int jj = 0; jj < 4; ++jj)                               \
      BA[nt][jj] = BF[(size_t)cbn_ * 16384 + (r0 + lk * 4 + jj) * 128 +            \
                      w * 32 + nt * 16 + lr];                                      \
  }                                                                                \
} while (0)

#define L2_STEP(BT, BA, CC, PBT, PBA) do {                                         \
  const int cb_ = (CC) * 8 + bh;                                                   \
  { const int idx = tid * 8, r = idx >> 7, jc = idx & 127;                         \
    f32x4 s0 = *(const f32x4*)&Scur[r * 132 + jc];                                 \
    f32x4 s1 = *(const f32x4*)&Scur[r * 132 + jc + 4];                             \
    *(bf16x8*)(SALL + (size_t)cb_ * 16384 + (r0 + r) * 128 + jc) = pack8(s0, s1); }\
  bf16x8 af[4];                                                                    \
  _Pragma("unroll") for (int ks = 0; ks < 4; ++ks)                                 \
    af[ks] = pack8(*(const f32x4*)&Scur[lr * 132 + ks * 32 + lk * 8],              \
                   *(const f32x4*)&Scur[lr * 132 + ks * 32 + lk * 8 + 4]);         \
  if ((CC) < 31) L2_PREFETCH(PBT, PBA, (CC) + 1);                                  \
  f32x4 acc0 = {}, acc1 = {};                                                      \
  _Pragma("unroll") for (int ks = 0; ks < 4; ++ks) {                               \
    acc0 = MFMA16(af[ks], BT[0][ks], acc0);                                        \
    acc1 = MFMA16(af[ks], BT[1][ks], acc1);                                        \
  }                                                                                \
  _Pragma("unroll") for (int jj = 0; jj < 4; ++jj) {                               \
    Snxt[(lk * 4 + jj) * 132 + w * 32 + lr]      = acc0[jj] + BA[0][jj];           \
    Snxt[(lk * 4 + jj) * 132 + w * 32 + 16 + lr] = acc1[jj] + BA[1][jj];           \
  }                                                                                \
  __syncthreads();                                                                 \
  { float* t_ = Scur; Scur = Snxt; Snxt = t_; }                                    \
} while (0)

__global__ __launch_bounds__(256)
void scan_state_kernel(const short* __restrict__ TRB, const float* __restrict__ BF,
                       const float* __restrict__ st0, short* __restrict__ SALL,
                       float* __restrict__ stout)
{
  __shared__ float Sl[2 * 16 * 132];
  const int bid = blockIdx.x;            // 64
  const int bh = bid & 7, slab = bid >> 3;
  const int r0 = slab * 16;
  const int tid = threadIdx.x, lane = tid & 63, w = tid >> 6;
  const int lr = lane & 15, lk = lane >> 4;

  float* Scur = Sl;
  float* Snxt = Sl + 16 * 132;

  {
    const int idx = tid * 8, r = idx >> 7, jc = idx & 127;
    const float* sp = st0 + ((size_t)bh * 128 + r0 + r) * 128 + jc;
    *(f32x4*)&Scur[r * 132 + jc]     = *(const f32x4*)sp;
    *(f32x4*)&Scur[r * 132 + jc + 4] = *(const f32x4*)(sp + 4);
  }
  bf16x8 btA[2][4], btB[2][4];
  float  baA[2][4], baB[2][4];
  L2_PREFETCH(btA, baA, 0);
  __syncthreads();

  for (int c2 = 0; c2 < 16; ++c2) {
    L2_STEP(btA, baA, 2 * c2,     btB, baB);
    L2_STEP(btB, baB, 2 * c2 + 1, btA, baA);
  }

  {
    const int idx = tid * 8, r = idx >> 7, jc = idx & 127;
    float* sp = stout + ((size_t)bh * 128 + r0 + r) * 128 + jc;
    *(f32x4*)sp       = *(const f32x4*)&Scur[r * 132 + jc];
    *(f32x4*)(sp + 4) = *(const f32x4*)&Scur[r * 132 + jc + 4];
  }
}

// ---------------- scan output: fully parallel over chunks ----------------
__global__ __launch_bounds__(512)
void scan_output_kernel(const __hip_bfloat16* __restrict__ qh,
                        const short* __restrict__ WTB, const __hip_bfloat16* __restrict__ ZB,
                        const short* __restrict__ PHB, const float* __restrict__ GV,
                        const short* __restrict__ SALL, __hip_bfloat16* __restrict__ obuf)
{
  __shared__ short Ut[128 * 72];
  const int cb = blockIdx.x;
  const int bh = cb & 7, c = cb >> 3;
  const int b = bh >> 2, h = bh & 3;
  const int tid = threadIdx.x, lane = tid & 63, w = tid >> 6;   // w 0..7
  const int lr = lane & 15, lk = lane >> 4;
  const int r0 = (w & 3) * 16;

  f32x4 Y[8] = {};
#pragma unroll
  for (int ks = 0; ks < 4; ++ks) {
    bf16x8 af;
    if (w < 4) {
      af = *(const bf16x8*)(qh + ((size_t)(b * LQ + c * CT) + r0 + lr) * 512 + h * 128 + ks * 32 + lk * 8);
    } else {
      af = *(const bf16x8*)(WTB + (size_t)cb * 8192 + (r0 + lr) * 128 + ks * 32 + lk * 8);
    }
#pragma unroll
    for (int nt = 0; nt < 8; ++nt) {
      const bf16x8 bs = *(const bf16x8*)(SALL + (size_t)cb * 16384 + (nt * 16 + lr) * 128 + ks * 32 + lk * 8);
      Y[nt] = MFMA16(af, bs, Y[nt]);
    }
  }
  if (w >= 4) {   // U = Z - Y_low -> LDS (Ut[i][s])
#pragma unroll
    for (int nt = 0; nt < 8; ++nt) {
      const int i = nt * 16 + lr;
      s16x4 up;
#pragma unroll
      for (int jj = 0; jj < 4; ++jj) {
        const int s = r0 + lk * 4 + jj;
        const float z = __bfloat162float(ZB[(size_t)cb * 8192 + s * 128 + i]);
        up[jj] = bf16s(z - Y[nt][jj]);
      }
      *(s16x4*)&Ut[i * 72 + r0 + lk * 4] = up;
    }
  }
  __syncthreads();
  if (w < 4) {
    f32x4 P2[8] = {};
#pragma unroll
    for (int ks = 0; ks < 2; ++ks) {
      const bf16x8 ap = *(const bf16x8*)(PHB + (size_t)cb * 4096 + (r0 + lr) * 64 + ks * 32 + lk * 8);
#pragma unroll
      for (int nt = 0; nt < 8; ++nt) {
        const bf16x8 bu = *(const bf16x8*)&Ut[(nt * 16 + lr) * 72 + ks * 32 + lk * 8];
        P2[nt] = MFMA16(ap, bu, P2[nt]);
      }
    }
    float gvv[4];
#pragma unroll
    for (int jj = 0; jj < 4; ++jj) gvv[jj] = GV[cb * 64 + r0 + lk * 4 + jj];
#pragma unroll
    for (int nt = 0; nt < 8; ++nt) {
      const int i = nt * 16 + lr;
#pragma unroll
      for (int jj = 0; jj < 4; ++jj) {
        const int t = r0 + lk * 4 + jj;
        ((unsigned short*)obuf)[((size_t)(b * LQ + c * CT) + t) * 512 + h * 128 + i] =
            (unsigned short)bf16s(gvv[jj] * Y[nt][jj] + P2[nt][jj]);
      }
    }
  }
}

// ---------------- gate * silu(g), LayerNorm(512), cast bf16 ----------------
__global__ __launch_bounds__(256)
void gate_ln_kernel(const __hip_bfloat16* __restrict__ obuf, const __hip_bfloat16* __restrict__ vg,
                    const __hip_bfloat16* __restrict__ C, const float* __restrict__ lnw,
                    const float* __restrict__ lnb, __hip_bfloat16* __restrict__ lno)
{
  const int bl = blockIdx.x, tid = threadIdx.x;
  const int c0 = tid * 2;
  __shared__ float red[8];
  const ushort2 ovu = *(const ushort2*)((const unsigned short*)obuf + (size_t)bl * 512 + c0);
  const ushort2 gvu = *(const ushort2*)((const unsigned short*)vg + (size_t)bl * 512 + c0);
  const ushort2 ggu = *(const ushort2*)((const unsigned short*)C + (size_t)bl * NPROJ + 2048 + c0);
  const float v0 = bfu2f(ovu.x) * bfu2f(gvu.x) * siluf(bfu2f(ggu.x));
  const float v1 = bfu2f(ovu.y) * bfu2f(gvu.y) * siluf(bfu2f(ggu.y));
  float s = v0 + v1;
  float s2 = fmaf(v1, v1, v0 * v0);
  float2 pr = make_float2(s, s2);
#pragma unroll
  for (int m = 1; m < 64; m <<= 1) { pr.x += __shfl_xor(pr.x, m); pr.y += __shfl_xor(pr.y, m); }
  if ((tid & 63) == 0) { red[(tid >> 6) * 2] = pr.x; red[(tid >> 6) * 2 + 1] = pr.y; }
  __syncthreads();
  const float S  = red[0] + red[2] + red[4] + red[6];
  const float S2 = red[1] + red[3] + red[5] + red[7];
  const float mu  = S * (1.f / 512.f);
  const float var = S2 * (1.f / 512.f) - mu * mu;
  const float rs  = rsqrtf(var + 1e-5f);
  const float2 lw = *(const float2*)(lnw + c0);
  const float2 lb = *(const float2*)(lnb + c0);
  __hip_bfloat16 o[2] = {
    __float2bfloat16(fmaf((v0 - mu) * rs, lw.x, lb.x)),
    __float2bfloat16(fmaf((v1 - mu) * rs, lw.y, lb.y)) };
  *(ushort2*)((unsigned short*)lno + (size_t)bl * 512 + c0) = *(ushort2*)o;
}

extern "C" void kernel_launch(void* const* d_in, const int* in_sizes, int n_in,
                              void* d_out, int out_size, void* d_ws, size_t ws_size,
                              hipStream_t stream)
{
  (void)in_sizes; (void)n_in; (void)out_size; (void)ws_size;
  const float* x    = (const float*)d_in[0];
  const float* st0  = (const float*)d_in[1];
  const float* Wq   = (const float*)d_in[2];
  const float* Wk   = (const float*)d_in[3];
  const float* Wv   = (const float*)d_in[4];
  const float* Wa   = (const float*)d_in[5];
  const float* Wb   = (const float*)d_in[6];
  const float* Wg   = (const float*)d_in[7];
  const float* Wo   = (const float*)d_in[8];
  const float* qcw  = (const float*)d_in[9];
  const float* qcb  = (const float*)d_in[10];
  const float* kcw  = (const float*)d_in[11];
  const float* kcb  = (const float*)d_in[12];
  const float* vcw  = (const float*)d_in[13];
  const float* vcb  = (const float*)d_in[14];
  const float* lnw  = (const float*)d_in[15];
  const float* lnb  = (const float*)d_in[16];
  float* out = (float*)d_out;

  // workspace layout (bytes); high-water ~95.2 MB
  char* ws = (char*)d_ws;
  __hip_bfloat16* XB   = (__hip_bfloat16*)(ws + 0);            // 4096x1024 bf16 (dead after proj GEMM)
  __hip_bfloat16* LNO  = (__hip_bfloat16*)(ws + 0);            // 4096x512 bf16 (aliases XB 1st half)
  short*          WTB  = (short*)(ws + 4194304);               // [256][64][128] bf16 (aliases XB 2nd half)
  __hip_bfloat16* WCAT = (__hip_bfloat16*)(ws + 8388608);      // 2816x1024 bf16 (5767168 B)
  __hip_bfloat16* WOB  = (__hip_bfloat16*)(ws + 14155776);     // 1024x512 bf16 (1 MB)
  __hip_bfloat16* CBUFH = (__hip_bfloat16*)(ws + 15204352);    // 4096x2816 bf16 (23068672 B)
  __hip_bfloat16* QH   = (__hip_bfloat16*)(ws + 38273024);     // 4096x512 bf16
  __hip_bfloat16* KH   = (__hip_bfloat16*)(ws + 42467328);     // 4096x512 bf16
  __hip_bfloat16* VM   = (__hip_bfloat16*)(ws + 46661632);     // 4096x512 bf16
  __hip_bfloat16* VG   = (__hip_bfloat16*)(ws + 50855936);     // 4096x512 bf16
  float* AL   = (float*)(ws + 55050240);                       // 4096x4
  float* BE   = (float*)(ws + 55115776);
  __hip_bfloat16* OBUF = (__hip_bfloat16*)(ws + 55181312);     // 4096x512 bf16 (written by scan_output)
  short* TRB  = (short*)(ws + 55181312);                       // [256][128][128] bf16 (aliases OBUF; dead before scan_output)
  short* PHB  = (short*)(ws + 63569920);                       // [256][64][64] bf16
  short* ZB   = (short*)(ws + 65667072);                       // [256][64][128] bf16
  float* GV   = (float*)(ws + 69861376);                       // [256][64]
  short* SALL = (short*)(ws + 69926912);                       // [256][128][128] bf16 chunk-start states
  float* ABF  = (float*)(ws + 78315520);                       // [4096][8] f32 alpha/beta logits
  float* BF   = (float*)(ws + 78446592);                       // [256][128][128] f32

  cast_all_kernel<<<7424, 256, 0, stream>>>(x, Wo, Wq, Wk, Wv, Wg, Wa, Wb, XB, WOB, WCAT);

  gemm_bt_kernel<__hip_bfloat16><<<352, 512, 0, stream>>>(
      XB, WCAT, CBUFH, BLQ, NPROJ, KPROJ, ABF, 2560);

  conv_act_kernel<<<512, 256, 0, stream>>>(CBUFH, ABF, qcw, qcb, kcw, kcb, vcw, vcb,
                                           QH, KH, VM, VG, AL, BE);

  scan_phaseA_kernel<<<256, 512, 0, stream>>>(QH, KH, VM, AL, BE,
                                              WTB, ZB, PHB, GV, TRB, BF);

  scan_state_kernel<<<64, 256, 0, stream>>>(TRB, BF, st0, SALL, out + 4194304);

  scan_output_kernel<<<256, 512, 0, stream>>>(QH, WTB, (const __hip_bfloat16*)ZB,
                                              PHB, GV, SALL, OBUF);

  gate_ln_kernel<<<BLQ, 256, 0, stream>>>(OBUF, VG, CBUFH, lnw, lnb, LNO);

  gemm_bt_kernel<float><<<128, 512, 0, stream>>>(
      LNO, WOB, out, BLQ, DMQ, TOTQ, nullptr, 0);
}

// Round 13
// 145.752 us; speedup vs baseline: 1.0266x; 1.0266x over previous
//
#include <hip/hip_runtime.h>
#include <hip/hip_bf16.h>

// Problem constants
#define BQ    2
#define LQ    2048
#define DMQ   1024
#define HQ    4
#define DHQ   128
#define TOTQ  512
#define BLQ   4096      // B*L
#define NPROJ 2688      // padded concat: Wq(512) Wk(512) Wv(1024) Wg(512) Wa(4) Wb(4) pad(120)
#define KPROJ 1024
#define CT    64        // scan chunk length
#define NCH   32        // chunks (LQ/CT)

typedef short bf16x8 __attribute__((ext_vector_type(8)));
typedef short s16x4  __attribute__((ext_vector_type(4)));
typedef float f32x4  __attribute__((ext_vector_type(4)));

#define MFMA16(a, b, c) __builtin_amdgcn_mfma_f32_16x16x32_bf16(a, b, c, 0, 0, 0)

__device__ __forceinline__ float siluf(float x) { return x / (1.f + __expf(-x)); }
__device__ __forceinline__ float sigf(float x)  { return 1.f / (1.f + __expf(-x)); }
__device__ __forceinline__ short bf16s(float x) {
  return __builtin_bit_cast(short, __float2bfloat16(x));
}
__device__ __forceinline__ float bfu2f(unsigned short u) {
  return __bfloat162float(__builtin_bit_cast(__hip_bfloat16, u));
}
__device__ __forceinline__ bf16x8 pack8(f32x4 a, f32x4 b) {
  bf16x8 r;
  r[0] = bf16s(a.x); r[1] = bf16s(a.y); r[2] = bf16s(a.z); r[3] = bf16s(a.w);
  r[4] = bf16s(b.x); r[5] = bf16s(b.y); r[6] = bf16s(b.z); r[7] = bf16s(b.w);
  return r;
}

// global -> LDS direct load, 16B per lane. LDS dest must be wave-uniform base;
// HW writes base + lane*16.
__device__ __forceinline__ void gload_lds16(const void* g, void* l) {
  __builtin_amdgcn_global_load_lds(
      (__attribute__((address_space(1))) void*)(unsigned long long)g,
      (__attribute__((address_space(3))) void*)(unsigned int)(unsigned long long)l,
      16, 0, 0);
}

// ---------------- merged casts: x->XB, Wo->WOB, Wcat (one launch) ----------------
__global__ __launch_bounds__(256)
void cast_all_kernel(const float* __restrict__ x, const float* __restrict__ Wo,
                     const float* __restrict__ Wq, const float* __restrict__ Wk,
                     const float* __restrict__ Wv, const float* __restrict__ Wg,
                     const float* __restrict__ Wa, const float* __restrict__ Wb,
                     __hip_bfloat16* __restrict__ XB, __hip_bfloat16* __restrict__ WOB,
                     __hip_bfloat16* __restrict__ Wcat)
{
  const int bid = blockIdx.x;
  const int tid = threadIdx.x;
  if (bid < 4096) {                      // x: 4096x1024 f32, 4/thread
    const int i = bid * 256 + tid;
    float4 v = ((const float4*)x)[i];
    __hip_bfloat16 o[4] = { __float2bfloat16(v.x), __float2bfloat16(v.y),
                            __float2bfloat16(v.z), __float2bfloat16(v.w) };
    *(ushort4*)((unsigned short*)XB + (size_t)i * 4) = *(ushort4*)o;
  } else if (bid < 4608) {               // Wo: 1024x512 f32
    const int i = (bid - 4096) * 256 + tid;
    float4 v = ((const float4*)Wo)[i];
    __hip_bfloat16 o[4] = { __float2bfloat16(v.x), __float2bfloat16(v.y),
                            __float2bfloat16(v.z), __float2bfloat16(v.w) };
    *(ushort4*)((unsigned short*)WOB + (size_t)i * 4) = *(ushort4*)o;
  } else {                               // Wcat: 2688 rows x 1024
    const int i4 = (bid - 4608) * 256 + tid;
    const int row = i4 >> 8;
    const int col = (i4 & 255) * 4;
    const int idx = row * 1024 + col;
    float4 v;
    if      (row < 512)  v = *(const float4*)(Wq + idx);
    else if (row < 1024) v = *(const float4*)(Wk + idx - 512 * 1024);
    else if (row < 2048) v = *(const float4*)(Wv + idx - 1024 * 1024);
    else if (row < 2560) v = *(const float4*)(Wg + idx - 2048 * 1024);
    else if (row < 2564) v = *(const float4*)(Wa + (row - 2560) * 1024 + col);
    else if (row < 2568) v = *(const float4*)(Wb + (row - 2564) * 1024 + col);
    else                 v = make_float4(0.f, 0.f, 0.f, 0.f);
    __hip_bfloat16 o[4] = { __float2bfloat16(v.x), __float2bfloat16(v.y),
                            __float2bfloat16(v.z), __float2bfloat16(v.w) };
    *(ushort4*)((unsigned short*)Wcat + idx) = *(ushort4*)o;
  }
}

// ---------------- bf16 MFMA GEMM: C(TOUT, MxN) = A(M,K) * B(N,K)^T ----------------
// 128x128 tile, 4 waves, 2-phase double-buffered LDS; 1D grid with bijective
// XCD-chunked swizzle (grid%8==0): each XCD walks a contiguous tn-major chunk
// so its B-panel stays L2-hot. Grid MUST be (M/128)*(N/128). TOUT = bf16/f32.
// If aux != nullptr, output columns [auxc0, auxc0+8) are ALSO stored f32 to
// aux[row*8 + (col-auxc0)] (keeps alpha/beta logits full-precision).
template <typename TOUT>
__global__ __launch_bounds__(256)
void gemm_bt_kernel(const __hip_bfloat16* __restrict__ A,
                    const __hip_bfloat16* __restrict__ Bw,
                    TOUT* __restrict__ C, int M, int N, int K,
                    float* __restrict__ aux, int auxc0)
{
  __shared__ __hip_bfloat16 As[2 * 128 * 32];
  __shared__ __hip_bfloat16 Bs[2 * 128 * 32];
  const int tid  = threadIdx.x;
  const int lane = tid & 63;
  const int w    = tid >> 6;
  const int wm   = w >> 1, wn = w & 1;
  const int nwg  = gridDim.x;
  const int bid  = blockIdx.x;
  const int wgid = (bid & 7) * (nwg >> 3) + (bid >> 3);   // XCD-chunked, bijective (nwg%8==0)
  const int tm   = wgid & 31;           // 32 M-tiles of 128 (M=4096)
  const int tn   = wgid >> 5;           // N-tiles of 128
  const int lr   = lane & 15, lk = lane >> 4;

  f32x4 acc[4][4] = {};

  const int e0   = tid * 8;
  const int srow = e0 >> 5;        // 0..63
  const int scol = e0 & 31;
  const __hip_bfloat16* Ap = A  + (size_t)(tm * 128 + srow) * K + scol;
  const __hip_bfloat16* Bp = Bw + (size_t)(tn * 128 + srow) * K + scol;
  char* AsB  = (char*)As;
  char* BsB  = (char*)Bs;
  const size_t half = (size_t)64 * K;
  const int nk = K >> 5;

  // prologue: stage K-tile 0 into buffer 0
  {
    char* AsD = AsB + w * 1024;
    char* BsD = BsB + w * 1024;
    gload_lds16(Ap,        AsD);
    gload_lds16(Ap + half, AsD + 4096);
    gload_lds16(Bp,        BsD);
    gload_lds16(Bp + half, BsD + 4096);
  }
  __syncthreads();

  for (int it = 0; it < nk; ++it) {
    const int sel = it & 1;
    // prefetch next K-tile into the other buffer (no wait here)
    if (it + 1 < nk) {
      const int kk = (it + 1) * 32;
      char* AsD = AsB + ((sel ^ 1) * 8192) + w * 1024;
      char* BsD = BsB + ((sel ^ 1) * 8192) + w * 1024;
      gload_lds16(Ap + kk,        AsD);
      gload_lds16(Ap + half + kk, AsD + 4096);
      gload_lds16(Bp + kk,        BsD);
      gload_lds16(Bp + half + kk, BsD + 4096);
    }
    // compute on current buffer
    const char* AsR = AsB + sel * 8192;
    const char* BsR = BsB + sel * 8192;
    bf16x8 af[4], bfv[4];
#pragma unroll
    for (int m = 0; m < 4; ++m)
      af[m]  = *(const bf16x8*)(AsR + ((wm * 64 + m * 16 + lr) * 32 + lk * 8) * 2);
#pragma unroll
    for (int n = 0; n < 4; ++n)
      bfv[n] = *(const bf16x8*)(BsR + ((wn * 64 + n * 16 + lr) * 32 + lk * 8) * 2);
#pragma unroll
    for (int m = 0; m < 4; ++m)
#pragma unroll
      for (int n = 0; n < 4; ++n)
        acc[m][n] = MFMA16(af[m], bfv[n], acc[m][n]);
    // barrier (drains vmcnt): next tile resident, current buffer reusable
    __syncthreads();
  }

  const int crow0 = tm * 128 + wm * 64 + (lane >> 4) * 4;
  const int ccol0 = tn * 128 + wn * 64 + lr;
#pragma unroll
  for (int m = 0; m < 4; ++m)
#pragma unroll
    for (int n = 0; n < 4; ++n) {
      const int cc = ccol0 + n * 16;
#pragma unroll
      for (int j = 0; j < 4; ++j) {
        const float v = acc[m][n][j];
        const size_t row = (size_t)(crow0 + m * 16 + j);
        if constexpr (sizeof(TOUT) == 2)
          ((unsigned short*)C)[row * N + cc] = (unsigned short)bf16s(v);
        else
          C[row * N + cc] = v;
        if (aux && cc >= auxc0 && cc < auxc0 + 8)
          aux[row * 8 + (cc - auxc0)] = v;
      }
    }
}

// ---------------- conv(4-tap causal) + silu + l2norm + sigmoid(a,b) ----------------
// Sliding-window over 8 timesteps per block (512 blocks). CBUF is bf16;
// alpha/beta logits come from the f32 side buffer abf. Outputs bf16.
__global__ __launch_bounds__(256)
void conv_act_kernel(const __hip_bfloat16* __restrict__ C, const float* __restrict__ abf,
                     const float* __restrict__ qcw, const float* __restrict__ qcb,
                     const float* __restrict__ kcw, const float* __restrict__ kcb,
                     const float* __restrict__ vcw, const float* __restrict__ vcb,
                     __hip_bfloat16* __restrict__ qh, __hip_bfloat16* __restrict__ kh,
                     __hip_bfloat16* __restrict__ vm, __hip_bfloat16* __restrict__ vg,
                     float* __restrict__ al, float* __restrict__ be)
{
  const int blk = blockIdx.x;           // 512
  const int bl0 = blk * 8;              // global row start (never crosses b: 2048%8==0)
  const int t0  = bl0 & (LQ - 1);       // local t start
  const int tid = threadIdx.x;
  const unsigned short* Cu = (const unsigned short*)C;
  __shared__ float red[4][16];

  float2 qv[8], kv[8];
  float sq[8], sk[8];
#pragma unroll
  for (int t = 0; t < 8; ++t) { sq[t] = 0.f; sk[t] = 0.f; }

  {
    const int c0 = tid * 2;
    const float4 wqA = *(const float4*)(qcw + 4 * c0);
    const float4 wqB = *(const float4*)(qcw + 4 * c0 + 4);
    const float4 wkA = *(const float4*)(kcw + 4 * c0);
    const float4 wkB = *(const float4*)(kcw + 4 * c0 + 4);
    const float2 bq = *(const float2*)(qcb + c0);
    const float2 bk = *(const float2*)(kcb + c0);
    float2 wrq[11], wrk[11];
#pragma unroll
    for (int r = 0; r < 11; ++r) {
      const int tt = t0 - 3 + r;
      if (tt >= 0) {
        const unsigned short* Cr = Cu + (size_t)(bl0 - 3 + r) * NPROJ;
        const ushort2 aq = *(const ushort2*)(Cr + c0);
        const ushort2 ak = *(const ushort2*)(Cr + 512 + c0);
        wrq[r] = make_float2(bfu2f(aq.x), bfu2f(aq.y));
        wrk[r] = make_float2(bfu2f(ak.x), bfu2f(ak.y));
      } else {
        wrq[r] = make_float2(0.f, 0.f);
        wrk[r] = make_float2(0.f, 0.f);
      }
    }
#pragma unroll
    for (int t = 0; t < 8; ++t) {
      float aq0 = bq.x, aq1 = bq.y, ak0 = bk.x, ak1 = bk.y;
#pragma unroll
      for (int j = 0; j < 4; ++j) {
        aq0 = fmaf(((const float*)&wqA)[j], wrq[t + j].x, aq0);
        aq1 = fmaf(((const float*)&wqB)[j], wrq[t + j].y, aq1);
        ak0 = fmaf(((const float*)&wkA)[j], wrk[t + j].x, ak0);
        ak1 = fmaf(((const float*)&wkB)[j], wrk[t + j].y, ak1);
      }
      const float q0 = siluf(aq0), q1 = siluf(aq1);
      const float k0 = siluf(ak0), k1 = siluf(ak1);
      qv[t] = make_float2(q0, q1);
      kv[t] = make_float2(k0, k1);
      sq[t] = fmaf(q1, q1, fmaf(q0, q0, sq[t]));
      sk[t] = fmaf(k1, k1, fmaf(k0, k0, sk[t]));
    }
  }
  // reduce sq,sk across 64 lanes, then across 4 waves
#pragma unroll
  for (int m = 1; m < 64; m <<= 1) {
#pragma unroll
    for (int t = 0; t < 8; ++t) {
      sq[t] += __shfl_xor(sq[t], m);
      sk[t] += __shfl_xor(sk[t], m);
    }
  }
  {
    const int w = tid >> 6, lane = tid & 63;
    if (lane == 0) {
#pragma unroll
      for (int t = 0; t < 8; ++t) { red[w][t] = sq[t]; red[w][8 + t] = sk[t]; }
    }
  }
  __syncthreads();
  float rnq[8], rnk[8];
#pragma unroll
  for (int t = 0; t < 8; ++t) {
    const float SQ = red[0][t] + red[1][t] + red[2][t] + red[3][t];
    const float SK = red[0][8 + t] + red[1][8 + t] + red[2][8 + t] + red[3][8 + t];
    rnq[t] = 1.f / fmaxf(sqrtf(SQ), 1e-12f);
    rnk[t] = 1.f / fmaxf(sqrtf(SK), 1e-12f);
  }
  {
    const int c0 = tid * 2;
#pragma unroll
    for (int t = 0; t < 8; ++t) {
      ushort2 oq, ok;
      oq.x = (unsigned short)bf16s(qv[t].x * rnq[t]);
      oq.y = (unsigned short)bf16s(qv[t].y * rnq[t]);
      ok.x = (unsigned short)bf16s(kv[t].x * rnk[t]);
      ok.y = (unsigned short)bf16s(kv[t].y * rnk[t]);
      *(ushort2*)((unsigned short*)qh + (size_t)(bl0 + t) * 512 + c0) = oq;
      *(ushort2*)((unsigned short*)kh + (size_t)(bl0 + t) * 512 + c0) = ok;
    }
  }
  // v: 4 consecutive channels per thread
  {
    const int cv = tid * 4;   // 0..1023
    const float4 wv0 = *(const float4*)(vcw + 4 * cv);
    const float4 wv1 = *(const float4*)(vcw + 4 * cv + 4);
    const float4 wv2 = *(const float4*)(vcw + 4 * cv + 8);
    const float4 wv3 = *(const float4*)(vcw + 4 * cv + 12);
    const float4 bv4 = *(const float4*)(vcb + cv);
    float4 wr[11];
#pragma unroll
    for (int r = 0; r < 11; ++r) {
      const int tt = t0 - 3 + r;
      if (tt >= 0) {
        const ushort4 u = *(const ushort4*)(Cu + (size_t)(bl0 - 3 + r) * NPROJ + 1024 + cv);
        wr[r] = make_float4(bfu2f(u.x), bfu2f(u.y), bfu2f(u.z), bfu2f(u.w));
      } else {
        wr[r] = make_float4(0.f, 0.f, 0.f, 0.f);
      }
    }
#pragma unroll
    for (int t = 0; t < 8; ++t) {
      float a0 = bv4.x, a1 = bv4.y, a2 = bv4.z, a3 = bv4.w;
#pragma unroll
      for (int j = 0; j < 4; ++j) {
        a0 = fmaf(((const float*)&wv0)[j], ((const float*)&wr[t + j])[0], a0);
        a1 = fmaf(((const float*)&wv1)[j], ((const float*)&wr[t + j])[1], a1);
        a2 = fmaf(((const float*)&wv2)[j], ((const float*)&wr[t + j])[2], a2);
        a3 = fmaf(((const float*)&wv3)[j], ((const float*)&wr[t + j])[3], a3);
      }
      ushort4 o;
      o.x = (unsigned short)bf16s(siluf(a0));
      o.y = (unsigned short)bf16s(siluf(a1));
      o.z = (unsigned short)bf16s(siluf(a2));
      o.w = (unsigned short)bf16s(siluf(a3));
      if (cv < 512) *(ushort4*)((unsigned short*)vm + (size_t)(bl0 + t) * 512 + cv)         = o;
      else          *(ushort4*)((unsigned short*)vg + (size_t)(bl0 + t) * 512 + (cv - 512)) = o;
    }
  }
  // alpha/beta from f32 side buffer: threads 0..63 cover 8 t x (4 al + 4 be)
  if (tid < 64) {
    const int t = tid >> 3;
    const int k = tid & 7;
    const float v = abf[(size_t)(bl0 + t) * 8 + k];
    if (k < 4) al[(size_t)(bl0 + t) * 4 + k]       = sigf(v);
    else       be[(size_t)(bl0 + t) * 4 + (k - 4)] = sigf(v);
  }
}

// ---------------- scan phase A (FUSED with transition), 512 threads ----------------
// 256 blocks = 32 chunks x 8 (b,h); 8 waves (2 waves/SIMD).
// Work split: G/Pq MFMA over 8 waves (t-band x s-half); substitution with TWO
// threads per column (A: rows 0-7 of each 16-block, B: rows 8-15, barrier
// handoff through the Xl spill); transition over 8 waves (row-band x col-qtr).
__global__ __launch_bounds__(512)
void scan_phaseA_kernel(const __hip_bfloat16* __restrict__ qh, const __hip_bfloat16* __restrict__ kh,
                        const __hip_bfloat16* __restrict__ vm, const float* __restrict__ al,
                        const float* __restrict__ be,
                        short* __restrict__ WTB, short* __restrict__ ZB,
                        short* __restrict__ PHB, float* __restrict__ GV,
                        short* __restrict__ TRB, float* __restrict__ BF)
{
  __shared__ char sm[136192];
  float* Xl = (float*)(sm);                             // [64][256] f32 (aliases KBl/QBl)
  __hip_bfloat16* KBl = (__hip_bfloat16*)(sm);          // [64][136]
  __hip_bfloat16* QBl = (__hip_bfloat16*)(sm + 17408);  // [64][136]
  float* Ll  = (float*)(sm + 65536);                    // [64][68]
  float* dv  = (float*)(sm + 82944);                    // [64]
  float* bv  = (float*)(sm + 83200);                    // [64]
  float* gbv = (float*)(sm + 83456);                    // [64]
  float* fvs = (float*)(sm + 83712);                    // [64]
  short* KTl  = (short*)(sm + 83968);                   // [128][68] bf16
  short* WTFl = (short*)(sm + 101376);                  // [128][68] bf16
  short* ZFl  = (short*)(sm + 118784);                  // [128][68] bf16

  const int cb = blockIdx.x;
  const int bh = cb & 7, c = cb >> 3;
  const int b = bh >> 2, h = bh & 3;
  const int tid = threadIdx.x;          // 0..511
  const int lane = tid & 63;
  const int w = tid >> 6;               // 0..7
  const int lr = lane & 15, lk = lane >> 4;
  const size_t rowbase = (size_t)(b * LQ + c * CT) * 512 + h * 128;

  // stage K,Q -> LDS bf16 (padded rows of 136); 2 reps of 512 threads
#pragma unroll
  for (int rep = 0; rep < 2; ++rep) {
    const int fid = tid + rep * 512;       // 0..1023
    const int r = fid >> 4;
    const int cg = (fid & 15) * 8;
    *(bf16x8*)(KBl + r * 136 + cg) = *(const bf16x8*)(kh + rowbase + (size_t)r * 512 + cg);
    *(bf16x8*)(QBl + r * 136 + cg) = *(const bf16x8*)(qh + rowbase + (size_t)r * 512 + cg);
  }
  // decay prefix (wave 0)
  if (w == 0) {
    float la = __logf(al[(size_t)(b * LQ + c * CT + lane) * 4 + h]);
    const float bb = be[(size_t)(b * LQ + c * CT + lane) * 4 + h];
#pragma unroll
    for (int off = 1; off < 64; off <<= 1) {
      const float tv = __shfl_up(la, off, 64);
      if (lane >= off) la += tv;
    }
    dv[lane] = la; bv[lane] = bb; gbv[lane] = bb * __expf(la);
    const float d63 = __shfl(la, 63, 64);
    fvs[lane] = __expf(d63 - la);
    GV[cb * 64 + lane] = __expf(la);
  }
  __syncthreads();

  // G = K K^T, Pq = Q K^T : wave w owns t-band (w&3) and s-half (w>>2)
  {
    const int tb = (w & 3) * 16;
    const int sh = (w >> 2) * 2;          // s-tile base (2 tiles per wave)
    f32x4 aG[2] = {}, aP[2] = {};
#pragma unroll
    for (int ks = 0; ks < 4; ++ks) {
      bf16x8 bk[2];
#pragma unroll
      for (int nt = 0; nt < 2; ++nt)
        bk[nt] = *(const bf16x8*)(KBl + ((sh + nt) * 16 + lr) * 136 + ks * 32 + lk * 8);
      const bf16x8 ak = *(const bf16x8*)(KBl + (tb + lr) * 136 + ks * 32 + lk * 8);
      const bf16x8 aq = *(const bf16x8*)(QBl + (tb + lr) * 136 + ks * 32 + lk * 8);
#pragma unroll
      for (int nt = 0; nt < 2; ++nt) {
        aG[nt] = MFMA16(ak, bk[nt], aG[nt]);
        aP[nt] = MFMA16(aq, bk[nt], aP[nt]);
      }
    }
#pragma unroll
    for (int nt = 0; nt < 2; ++nt)
#pragma unroll
      for (int jj = 0; jj < 4; ++jj) {
        const int t = tb + lk * 4 + jj;
        const int s = (sh + nt) * 16 + lr;
        const float eg = __expf(dv[t] - dv[s]);
        Ll[t * 68 + s] = (t > s) ? bv[t] * eg * aG[nt][jj] : 0.f;
        PHB[(size_t)cb * 4096 + t * 64 + s] = (s <= t) ? bf16s(eg * aP[nt][jj]) : (short)0;
      }
  }
  // KT (LDS) = K^T from staged KBl, BEFORE Xl overwrites it
  if (tid < 128) {
    const short* Kbs = (const short*)KBl;
#pragma unroll
    for (int s4 = 0; s4 < 16; ++s4) {
      s16x4 pk;
#pragma unroll
      for (int e = 0; e < 4; ++e)
        pk[e] = Kbs[(s4 * 4 + e) * 136 + tid];
      *(s16x4*)(KTl + tid * 68 + s4 * 4) = pk;
    }
  }
  __syncthreads();   // KBl/QBl dead from here -> Xl may overwrite

  // ---- blocked forward substitution: 2 threads per column ----
  const int j = tid & 255;
  const int half = tid >> 8;
  const int i0 = half * 8;
  const __hip_bfloat16* src = (j < 128) ? kh : vm;
  const __hip_bfloat16* xp = src + rowbase + (j & 127);
  float* XlC = Xl + j;                 // private column, stride 256 floats
  short* dstN = (j < 128) ? (WTB + (size_t)cb * 8192 + j)
                          : (ZB  + (size_t)cb * 8192 + (j - 128));
  short* dstT = (j < 128) ? (WTFl + j * 68)
                          : (ZFl  + (j - 128) * 68);

  for (int r = 0; r < 4; ++r) {
    float u[8];
#pragma unroll
    for (int i = 0; i < 8; ++i) {
      const int t = r * 16 + i0 + i;
      u[i] = __bfloat162float(xp[(size_t)t * 512]) * ((j < 128) ? gbv[t] : bv[t]);
    }
    for (int sc = 0; sc < r; ++sc) {
      float xs[16];
#pragma unroll
      for (int k = 0; k < 16; ++k) xs[k] = XlC[(sc * 16 + k) * 256];
#pragma unroll
      for (int i = 0; i < 8; ++i) {
        const float* lrow = Ll + (r * 16 + i0 + i) * 68 + sc * 16;
        const f32x4 l0 = *(const f32x4*)(lrow);
        const f32x4 l1 = *(const f32x4*)(lrow + 4);
        const f32x4 l2 = *(const f32x4*)(lrow + 8);
        const f32x4 l3 = *(const f32x4*)(lrow + 12);
        f32x4 acc = {};
        acc.x = fmaf(l0.x, xs[0],  acc.x); acc.y = fmaf(l0.y, xs[1],  acc.y);
        acc.z = fmaf(l0.z, xs[2],  acc.z); acc.w = fmaf(l0.w, xs[3],  acc.w);
        acc.x = fmaf(l1.x, xs[4],  acc.x); acc.y = fmaf(l1.y, xs[5],  acc.y);
        acc.z = fmaf(l1.z, xs[6],  acc.z); acc.w = fmaf(l1.w, xs[7],  acc.w);
        acc.x = fmaf(l2.x, xs[8],  acc.x); acc.y = fmaf(l2.y, xs[9],  acc.y);
        acc.z = fmaf(l2.z, xs[10], acc.z); acc.w = fmaf(l2.w, xs[11], acc.w);
        acc.x = fmaf(l3.x, xs[12], acc.x); acc.y = fmaf(l3.y, xs[13], acc.y);
        acc.z = fmaf(l3.z, xs[14], acc.z); acc.w = fmaf(l3.w, xs[15], acc.w);
        u[i] -= (acc.x + acc.y) + (acc.z + acc.w);
      }
    }
    if (half == 0) {
#pragma unroll
      for (int i = 1; i < 8; ++i) {
        const float* lrow = Ll + (r * 16 + i) * 68 + r * 16;
        f32x4 acc = {};
#pragma unroll
        for (int k4 = 0; k4 < 2; ++k4) {
          if (k4 * 4 < i) {
            const f32x4 lv = *(const f32x4*)(lrow + k4 * 4);
            acc.x = fmaf(lv.x, u[k4 * 4 + 0], acc.x);
            acc.y = fmaf(lv.y, u[k4 * 4 + 1], acc.y);
            acc.z = fmaf(lv.z, u[k4 * 4 + 2], acc.z);
            acc.w = fmaf(lv.w, u[k4 * 4 + 3], acc.w);
          }
        }
        u[i] -= (acc.x + acc.y) + (acc.z + acc.w);
      }
#pragma unroll
      for (int i = 0; i < 8; ++i) XlC[(r * 16 + i) * 256] = u[i];
#pragma unroll
      for (int i = 0; i < 8; ++i) dstN[(r * 16 + i) * 128] = bf16s(u[i]);
#pragma unroll
      for (int s4 = 0; s4 < 2; ++s4) {
        s16x4 p;
#pragma unroll
        for (int e = 0; e < 4; ++e)
          p[e] = bf16s(fvs[r * 16 + s4 * 4 + e] * u[s4 * 4 + e]);
        *(s16x4*)(dstT + r * 16 + s4 * 4) = p;
      }
    }
    __syncthreads();   // A-half spill visible
    if (half == 1) {
      float xa[8];
#pragma unroll
      for (int k = 0; k < 8; ++k) xa[k] = XlC[(r * 16 + k) * 256];
#pragma unroll
      for (int i = 0; i < 8; ++i) {
        const float* lrow = Ll + (r * 16 + 8 + i) * 68 + r * 16;
        const f32x4 l0 = *(const f32x4*)(lrow);
        const f32x4 l1 = *(const f32x4*)(lrow + 4);
        f32x4 acc = {};
        acc.x = fmaf(l0.x, xa[0], acc.x); acc.y = fmaf(l0.y, xa[1], acc.y);
        acc.z = fmaf(l0.z, xa[2], acc.z); acc.w = fmaf(l0.w, xa[3], acc.w);
        acc.x = fmaf(l1.x, xa[4], acc.x); acc.y = fmaf(l1.y, xa[5], acc.y);
        acc.z = fmaf(l1.z, xa[6], acc.z); acc.w = fmaf(l1.w, xa[7], acc.w);
        u[i] -= (acc.x + acc.y) + (acc.z + acc.w);
      }
#pragma unroll
      for (int i = 1; i < 8; ++i) {
        const float* lrow = Ll + (r * 16 + 8 + i) * 68 + r * 16 + 8;
        f32x4 acc = {};
#pragma unroll
        for (int k4 = 0; k4 < 2; ++k4) {
          if (k4 * 4 < i) {
            const f32x4 lv = *(const f32x4*)(lrow + k4 * 4);
            acc.x = fmaf(lv.x, u[k4 * 4 + 0], acc.x);
            acc.y = fmaf(lv.y, u[k4 * 4 + 1], acc.y);
            acc.z = fmaf(lv.z, u[k4 * 4 + 2], acc.z);
            acc.w = fmaf(lv.w, u[k4 * 4 + 3], acc.w);
          }
        }
        u[i] -= (acc.x + acc.y) + (acc.z + acc.w);
      }
#pragma unroll
      for (int i = 0; i < 8; ++i) XlC[(r * 16 + 8 + i) * 256] = u[i];
#pragma unroll
      for (int i = 0; i < 8; ++i) dstN[(r * 16 + 8 + i) * 128] = bf16s(u[i]);
#pragma unroll
      for (int s4 = 0; s4 < 2; ++s4) {
        s16x4 p;
#pragma unroll
        for (int e = 0; e < 4; ++e)
          p[e] = bf16s(fvs[r * 16 + 8 + s4 * 4 + e] * u[s4 * 4 + e]);
        *(s16x4*)(dstT + r * 16 + 8 + s4 * 4) = p;
      }
    }
    __syncthreads();   // block r fully solved
  }

  // ---- fused transition: 8 waves, wave w owns row-band (w&3) x col-quarter (w>>2)
  const float gc = __expf(dv[63]);
  const int rb = (w & 3) * 32;
  const int cq = (w >> 2) * 4;
  {
    f32x4 acc[2][4] = {};
#pragma unroll
    for (int ks = 0; ks < 2; ++ks) {
      const bf16x8 a0 = *(const bf16x8*)(KTl + (rb + lr) * 68 + ks * 32 + lk * 8);
      const bf16x8 a1 = *(const bf16x8*)(KTl + (rb + 16 + lr) * 68 + ks * 32 + lk * 8);
#pragma unroll
      for (int nt = 0; nt < 4; ++nt) {
        const bf16x8 bm = *(const bf16x8*)(WTFl + ((cq + nt) * 16 + lr) * 68 + ks * 32 + lk * 8);
        acc[0][nt] = MFMA16(a0, bm, acc[0][nt]);
        acc[1][nt] = MFMA16(a1, bm, acc[1][nt]);
      }
    }
#pragma unroll
    for (int mt = 0; mt < 2; ++mt)
#pragma unroll
      for (int nt = 0; nt < 4; ++nt)
#pragma unroll
        for (int jj = 0; jj < 4; ++jj) {
          const int jr = rb + mt * 16 + lk * 4 + jj;
          const int m  = (cq + nt) * 16 + lr;
          const float v = ((jr == m) ? gc : 0.f) - acc[mt][nt][jj];
          TRB[(size_t)cb * 16384 + jr * 128 + m] = bf16s(v);
        }
  }
  {
    f32x4 acc[2][4] = {};
#pragma unroll
    for (int ks = 0; ks < 2; ++ks) {
      const bf16x8 a0 = *(const bf16x8*)(ZFl + (rb + lr) * 68 + ks * 32 + lk * 8);
      const bf16x8 a1 = *(const bf16x8*)(ZFl + (rb + 16 + lr) * 68 + ks * 32 + lk * 8);
#pragma unroll
      for (int nt = 0; nt < 4; ++nt) {
        const bf16x8 bj = *(const bf16x8*)(KTl + ((cq + nt) * 16 + lr) * 68 + ks * 32 + lk * 8);
        acc[0][nt] = MFMA16(a0, bj, acc[0][nt]);
        acc[1][nt] = MFMA16(a1, bj, acc[1][nt]);
      }
    }
#pragma unroll
    for (int mt = 0; mt < 2; ++mt)
#pragma unroll
      for (int nt = 0; nt < 4; ++nt)
#pragma unroll
        for (int jj = 0; jj < 4; ++jj) {
          const int ir = rb + mt * 16 + lk * 4 + jj;
          const int jc = (cq + nt) * 16 + lr;
          BF[(size_t)cb * 16384 + ir * 128 + jc] = acc[mt][nt][jj];
        }
  }
}

// ---------------- scan state: serial chunk recurrence, S rows independent ----
#define L2_PREFETCH(BT, BA, CC) do {                                               \
  const int cbn_ = (CC) * 8 + bh;                                                  \
  _Pragma("unroll") for (int nt = 0; nt < 2; ++nt) {                               \
    _Pragma("unroll") for (int ks = 0; ks < 4; ++ks)                               \
      BT[nt][ks] = *(const bf16x8*)(TRB + (size_t)cbn_ * 16384 +                   \
                                    (w * 32 + nt * 16 + lr) * 128 + ks * 32 + lk * 8); \
    _Pragma("unroll") for (int jj = 0; jj < 4; ++jj)                               \
      BA[nt][jj] = BF[(size_t)cbn_ * 16384 + (r0 + lk * 4 + jj) * 128 +            \
                      w * 32 + nt * 16 + lr];                                      \
  }                                                                                \
} while (0)

#define L2_STEP(BT, BA, CC, PBT, PBA) do {                                         \
  const int cb_ = (CC) * 8 + bh;                                                   \
  { const int idx = tid * 8, r = idx >> 7, jc = idx & 127;                         \
    f32x4 s0 = *(const f32x4*)&Scur[r * 132 + jc];                                 \
    f32x4 s1 = *(const f32x4*)&Scur[r * 132 + jc + 4];                             \
    *(bf16x8*)(SALL + (size_t)cb_ * 16384 + (r0 + r) * 128 + jc) = pack8(s0, s1); }\
  bf16x8 af[4];                                                                    \
  _Pragma("unroll") for (int ks = 0; ks < 4; ++ks)                                 \
    af[ks] = pack8(*(const f32x4*)&Scur[lr * 132 + ks * 32 + lk * 8],              \
                   *(const f32x4*)&Scur[lr * 132 + ks * 32 + lk * 8 + 4]);         \
  if ((CC) < 31) L2_PREFETCH(PBT, PBA, (CC) + 1);                                  \
  f32x4 acc0 = {}, acc1 = {};                                                      \
  _Pragma("unroll") for (int ks = 0; ks < 4; ++ks) {                               \
    acc0 = MFMA16(af[ks], BT[0][ks], acc0);                                        \
    acc1 = MFMA16(af[ks], BT[1][ks], acc1);                                        \
  }                                                                                \
  _Pragma("unroll") for (int jj = 0; jj < 4; ++jj) {                               \
    Snxt[(lk * 4 + jj) * 132 + w * 32 + lr]      = acc0[jj] + BA[0][jj];           \
    Snxt[(lk * 4 + jj) * 132 + w * 32 + 16 + lr] = acc1[jj] + BA[1][jj];           \
  }                                                                                \
  __syncthreads();                                                                 \
  { float* t_ = Scur; Scur = Snxt; Snxt = t_; }                                    \
} while (0)

__global__ __launch_bounds__(256)
void scan_state_kernel(const short* __restrict__ TRB, const float* __restrict__ BF,
                       const float* __restrict__ st0, short* __restrict__ SALL,
                       float* __restrict__ stout)
{
  __shared__ float Sl[2 * 16 * 132];
  const int bid = blockIdx.x;            // 64
  const int bh = bid & 7, slab = bid >> 3;
  const int r0 = slab * 16;
  const int tid = threadIdx.x, lane = tid & 63, w = tid >> 6;
  const int lr = lane & 15, lk = lane >> 4;

  float* Scur = Sl;
  float* Snxt = Sl + 16 * 132;

  {
    const int idx = tid * 8, r = idx >> 7, jc = idx & 127;
    const float* sp = st0 + ((size_t)bh * 128 + r0 + r) * 128 + jc;
    *(f32x4*)&Scur[r * 132 + jc]     = *(const f32x4*)sp;
    *(f32x4*)&Scur[r * 132 + jc + 4] = *(const f32x4*)(sp + 4);
  }
  bf16x8 btA[2][4], btB[2][4];
  float  baA[2][4], baB[2][4];
  L2_PREFETCH(btA, baA, 0);
  __syncthreads();

  for (int c2 = 0; c2 < 16; ++c2) {
    L2_STEP(btA, baA, 2 * c2,     btB, baB);
    L2_STEP(btB, baB, 2 * c2 + 1, btA, baA);
  }

  {
    const int idx = tid * 8, r = idx >> 7, jc = idx & 127;
    float* sp = stout + ((size_t)bh * 128 + r0 + r) * 128 + jc;
    *(f32x4*)sp       = *(const f32x4*)&Scur[r * 132 + jc];
    *(f32x4*)(sp + 4) = *(const f32x4*)&Scur[r * 132 + jc + 4];
  }
}

// ---------------- scan output: fully parallel over chunks ----------------
__global__ __launch_bounds__(512)
void scan_output_kernel(const __hip_bfloat16* __restrict__ qh,
                        const short* __restrict__ WTB, const __hip_bfloat16* __restrict__ ZB,
                        const short* __restrict__ PHB, const float* __restrict__ GV,
                        const short* __restrict__ SALL, __hip_bfloat16* __restrict__ obuf)
{
  __shared__ short Ut[128 * 72];
  const int cb = blockIdx.x;
  const int bh = cb & 7, c = cb >> 3;
  const int b = bh >> 2, h = bh & 3;
  const int tid = threadIdx.x, lane = tid & 63, w = tid >> 6;   // w 0..7
  const int lr = lane & 15, lk = lane >> 4;
  const int r0 = (w & 3) * 16;

  f32x4 Y[8] = {};
#pragma unroll
  for (int ks = 0; ks < 4; ++ks) {
    bf16x8 af;
    if (w < 4) {
      af = *(const bf16x8*)(qh + ((size_t)(b * LQ + c * CT) + r0 + lr) * 512 + h * 128 + ks * 32 + lk * 8);
    } else {
      af = *(const bf16x8*)(WTB + (size_t)cb * 8192 + (r0 + lr) * 128 + ks * 32 + lk * 8);
    }
#pragma unroll
    for (int nt = 0; nt < 8; ++nt) {
      const bf16x8 bs = *(const bf16x8*)(SALL + (size_t)cb * 16384 + (nt * 16 + lr) * 128 + ks * 32 + lk * 8);
      Y[nt] = MFMA16(af, bs, Y[nt]);
    }
  }
  if (w >= 4) {   // U = Z - Y_low -> LDS (Ut[i][s])
#pragma unroll
    for (int nt = 0; nt < 8; ++nt) {
      const int i = nt * 16 + lr;
      s16x4 up;
#pragma unroll
      for (int jj = 0; jj < 4; ++jj) {
        const int s = r0 + lk * 4 + jj;
        const float z = __bfloat162float(ZB[(size_t)cb * 8192 + s * 128 + i]);
        up[jj] = bf16s(z - Y[nt][jj]);
      }
      *(s16x4*)&Ut[i * 72 + r0 + lk * 4] = up;
    }
  }
  __syncthreads();
  if (w < 4) {
    f32x4 P2[8] = {};
#pragma unroll
    for (int ks = 0; ks < 2; ++ks) {
      const bf16x8 ap = *(const bf16x8*)(PHB + (size_t)cb * 4096 + (r0 + lr) * 64 + ks * 32 + lk * 8);
#pragma unroll
      for (int nt = 0; nt < 8; ++nt) {
        const bf16x8 bu = *(const bf16x8*)&Ut[(nt * 16 + lr) * 72 + ks * 32 + lk * 8];
        P2[nt] = MFMA16(ap, bu, P2[nt]);
      }
    }
    float gvv[4];
#pragma unroll
    for (int jj = 0; jj < 4; ++jj) gvv[jj] = GV[cb * 64 + r0 + lk * 4 + jj];
#pragma unroll
    for (int nt = 0; nt < 8; ++nt) {
      const int i = nt * 16 + lr;
#pragma unroll
      for (int jj = 0; jj < 4; ++jj) {
        const int t = r0 + lk * 4 + jj;
        ((unsigned short*)obuf)[((size_t)(b * LQ + c * CT) + t) * 512 + h * 128 + i] =
            (unsigned short)bf16s(gvv[jj] * Y[nt][jj] + P2[nt][jj]);
      }
    }
  }
}

// ---------------- gate * silu(g), LayerNorm(512), cast bf16 ----------------
__global__ __launch_bounds__(256)
void gate_ln_kernel(const __hip_bfloat16* __restrict__ obuf, const __hip_bfloat16* __restrict__ vg,
                    const __hip_bfloat16* __restrict__ C, const float* __restrict__ lnw,
                    const float* __restrict__ lnb, __hip_bfloat16* __restrict__ lno)
{
  const int bl = blockIdx.x, tid = threadIdx.x;
  const int c0 = tid * 2;
  __shared__ float red[8];
  const ushort2 ovu = *(const ushort2*)((const unsigned short*)obuf + (size_t)bl * 512 + c0);
  const ushort2 gvu = *(const ushort2*)((const unsigned short*)vg + (size_t)bl * 512 + c0);
  const ushort2 ggu = *(const ushort2*)((const unsigned short*)C + (size_t)bl * NPROJ + 2048 + c0);
  const float v0 = bfu2f(ovu.x) * bfu2f(gvu.x) * siluf(bfu2f(ggu.x));
  const float v1 = bfu2f(ovu.y) * bfu2f(gvu.y) * siluf(bfu2f(ggu.y));
  float s = v0 + v1;
  float s2 = fmaf(v1, v1, v0 * v0);
  float2 pr = make_float2(s, s2);
#pragma unroll
  for (int m = 1; m < 64; m <<= 1) { pr.x += __shfl_xor(pr.x, m); pr.y += __shfl_xor(pr.y, m); }
  if ((tid & 63) == 0) { red[(tid >> 6) * 2] = pr.x; red[(tid >> 6) * 2 + 1] = pr.y; }
  __syncthreads();
  const float S  = red[0] + red[2] + red[4] + red[6];
  const float S2 = red[1] + red[3] + red[5] + red[7];
  const float mu  = S * (1.f / 512.f);
  const float var = S2 * (1.f / 512.f) - mu * mu;
  const float rs  = rsqrtf(var + 1e-5f);
  const float2 lw = *(const float2*)(lnw + c0);
  const float2 lb = *(const float2*)(lnb + c0);
  __hip_bfloat16 o[2] = {
    __float2bfloat16(fmaf((v0 - mu) * rs, lw.x, lb.x)),
    __float2bfloat16(fmaf((v1 - mu) * rs, lw.y, lb.y)) };
  *(ushort2*)((unsigned short*)lno + (size_t)bl * 512 + c0) = *(ushort2*)o;
}

extern "C" void kernel_launch(void* const* d_in, const int* in_sizes, int n_in,
                              void* d_out, int out_size, void* d_ws, size_t ws_size,
                              hipStream_t stream)
{
  (void)in_sizes; (void)n_in; (void)out_size; (void)ws_size;
  const float* x    = (const float*)d_in[0];
  const float* st0  = (const float*)d_in[1];
  const float* Wq   = (const float*)d_in[2];
  const float* Wk   = (const float*)d_in[3];
  const float* Wv   = (const float*)d_in[4];
  const float* Wa   = (const float*)d_in[5];
  const float* Wb   = (const float*)d_in[6];
  const float* Wg   = (const float*)d_in[7];
  const float* Wo   = (const float*)d_in[8];
  const float* qcw  = (const float*)d_in[9];
  const float* qcb  = (const float*)d_in[10];
  const float* kcw  = (const float*)d_in[11];
  const float* kcb  = (const float*)d_in[12];
  const float* vcw  = (const float*)d_in[13];
  const float* vcb  = (const float*)d_in[14];
  const float* lnw  = (const float*)d_in[15];
  const float* lnb  = (const float*)d_in[16];
  float* out = (float*)d_out;

  // workspace layout (bytes); high-water ~141.2 MB
  char* ws = (char*)d_ws;
  __hip_bfloat16* XB   = (__hip_bfloat16*)(ws + 0);            // 4096x1024 bf16 (dead after proj GEMM)
  __hip_bfloat16* LNO  = (__hip_bfloat16*)(ws + 0);            // 4096x512 bf16 (aliases XB 1st half)
  short*          WTB  = (short*)(ws + 4194304);               // [256][64][128] bf16 (aliases XB 2nd half)
  __hip_bfloat16* WCAT = (__hip_bfloat16*)(ws + 8388608);      // 2688x1024 bf16
  __hip_bfloat16* WOB  = (__hip_bfloat16*)(ws + 13893632);     // 1024x512  bf16
  __hip_bfloat16* CBUFH = (__hip_bfloat16*)(ws + 14942208);    // 4096x2688 bf16
  __hip_bfloat16* QH   = (__hip_bfloat16*)(ws + 58982400);     // 4096x512 bf16
  __hip_bfloat16* KH   = (__hip_bfloat16*)(ws + 67371008);     // 4096x512 bf16
  __hip_bfloat16* VM   = (__hip_bfloat16*)(ws + 75759616);     // 4096x512 bf16
  __hip_bfloat16* VG   = (__hip_bfloat16*)(ws + 84148224);     // 4096x512 bf16
  float* AL   = (float*)(ws + 92536832);                       // 4096x4
  float* BE   = (float*)(ws + 92602368);
  __hip_bfloat16* OBUF = (__hip_bfloat16*)(ws + 92667904);     // 4096x512 bf16 (written by scan_output)
  short* TRB  = (short*)(ws + 92667904);                       // [256][128][128] bf16 (aliases OBUF; dead before scan_output)
  short* PHB  = (short*)(ws + 105250816);                      // [256][64][64] bf16
  short* ZB   = (short*)(ws + 107347968);                      // [256][64][128] bf16
  float* GV   = (float*)(ws + 111542272);                      // [256][64]
  short* SALL = (short*)(ws + 115868672);                      // [256][128][128] bf16 chunk-start states
  float* ABF  = (float*)(ws + 124257280);                      // [4096][8] f32 alpha/beta logits
  float* BF   = (float*)(ws + 124388352);                      // [256][128][128] f32 (fresh region; no aliasing)

  cast_all_kernel<<<7296, 256, 0, stream>>>(x, Wo, Wq, Wk, Wv, Wg, Wa, Wb, XB, WOB, WCAT);

  gemm_bt_kernel<__hip_bfloat16><<<672, 256, 0, stream>>>(
      XB, WCAT, CBUFH, BLQ, NPROJ, KPROJ, ABF, 2560);

  conv_act_kernel<<<512, 256, 0, stream>>>(CBUFH, ABF, qcw, qcb, kcw, kcb, vcw, vcb,
                                           QH, KH, VM, VG, AL, BE);

  scan_phaseA_kernel<<<256, 512, 0, stream>>>(QH, KH, VM, AL, BE,
                                              WTB, ZB, PHB, GV, TRB, BF);

  scan_state_kernel<<<64, 256, 0, stream>>>(TRB, BF, st0, SALL, out + 4194304);

  scan_output_kernel<<<256, 512, 0, stream>>>(QH, WTB, (const __hip_bfloat16*)ZB,
                                              PHB, GV, SALL, OBUF);

  gate_ln_kernel<<<BLQ, 256, 0, stream>>>(OBUF, VG, CBUFH, lnw, lnb, LNO);

  // 32 M-tiles x 8 N-tiles (N = DMQ = 1024) -> 256 blocks
  gemm_bt_kernel<float><<<256, 256, 0, stream>>>(
      LNO, WOB, out, BLQ, DMQ, TOTQ, nullptr, 0);
}

// Round 14
// 145.373 us; speedup vs baseline: 1.0293x; 1.0026x over previous
//
#include <hip/hip_runtime.h>
#include <hip/hip_bf16.h>

// Problem constants
#define BQ    2
#define LQ    2048
#define DMQ   1024
#define HQ    4
#define DHQ   128
#define TOTQ  512
#define BLQ   4096      // B*L
#define NPROJ 2688      // padded concat: Wq(512) Wk(512) Wv(1024) Wg(512) Wa(4) Wb(4) pad(120)
#define KPROJ 1024
#define CT    64        // scan chunk length
#define NCH   32        // chunks (LQ/CT)

typedef short bf16x8 __attribute__((ext_vector_type(8)));
typedef short s16x4  __attribute__((ext_vector_type(4)));
typedef float f32x4  __attribute__((ext_vector_type(4)));

#define MFMA16(a, b, c) __builtin_amdgcn_mfma_f32_16x16x32_bf16(a, b, c, 0, 0, 0)

__device__ __forceinline__ float siluf(float x) { return x / (1.f + __expf(-x)); }
__device__ __forceinline__ float sigf(float x)  { return 1.f / (1.f + __expf(-x)); }
__device__ __forceinline__ short bf16s(float x) {
  return __builtin_bit_cast(short, __float2bfloat16(x));
}
__device__ __forceinline__ float bfu2f(unsigned short u) {
  return __bfloat162float(__builtin_bit_cast(__hip_bfloat16, u));
}
__device__ __forceinline__ bf16x8 pack8(f32x4 a, f32x4 b) {
  bf16x8 r;
  r[0] = bf16s(a.x); r[1] = bf16s(a.y); r[2] = bf16s(a.z); r[3] = bf16s(a.w);
  r[4] = bf16s(b.x); r[5] = bf16s(b.y); r[6] = bf16s(b.z); r[7] = bf16s(b.w);
  return r;
}

// global -> LDS direct load, 16B per lane. LDS dest must be wave-uniform base;
// HW writes base + lane*16.
__device__ __forceinline__ void gload_lds16(const void* g, void* l) {
  __builtin_amdgcn_global_load_lds(
      (__attribute__((address_space(1))) void*)(unsigned long long)g,
      (__attribute__((address_space(3))) void*)(unsigned int)(unsigned long long)l,
      16, 0, 0);
}

// ---------------- merged casts: x->XB, Wo->WOB, Wcat (one launch) ----------------
__global__ __launch_bounds__(256)
void cast_all_kernel(const float* __restrict__ x, const float* __restrict__ Wo,
                     const float* __restrict__ Wq, const float* __restrict__ Wk,
                     const float* __restrict__ Wv, const float* __restrict__ Wg,
                     const float* __restrict__ Wa, const float* __restrict__ Wb,
                     __hip_bfloat16* __restrict__ XB, __hip_bfloat16* __restrict__ WOB,
                     __hip_bfloat16* __restrict__ Wcat)
{
  const int bid = blockIdx.x;
  const int tid = threadIdx.x;
  if (bid < 4096) {                      // x: 4096x1024 f32, 4/thread
    const int i = bid * 256 + tid;
    float4 v = ((const float4*)x)[i];
    __hip_bfloat16 o[4] = { __float2bfloat16(v.x), __float2bfloat16(v.y),
                            __float2bfloat16(v.z), __float2bfloat16(v.w) };
    *(ushort4*)((unsigned short*)XB + (size_t)i * 4) = *(ushort4*)o;
  } else if (bid < 4608) {               // Wo: 1024x512 f32
    const int i = (bid - 4096) * 256 + tid;
    float4 v = ((const float4*)Wo)[i];
    __hip_bfloat16 o[4] = { __float2bfloat16(v.x), __float2bfloat16(v.y),
                            __float2bfloat16(v.z), __float2bfloat16(v.w) };
    *(ushort4*)((unsigned short*)WOB + (size_t)i * 4) = *(ushort4*)o;
  } else {                               // Wcat: 2688 rows x 1024
    const int i4 = (bid - 4608) * 256 + tid;
    const int row = i4 >> 8;
    const int col = (i4 & 255) * 4;
    const int idx = row * 1024 + col;
    float4 v;
    if      (row < 512)  v = *(const float4*)(Wq + idx);
    else if (row < 1024) v = *(const float4*)(Wk + idx - 512 * 1024);
    else if (row < 2048) v = *(const float4*)(Wv + idx - 1024 * 1024);
    else if (row < 2560) v = *(const float4*)(Wg + idx - 2048 * 1024);
    else if (row < 2564) v = *(const float4*)(Wa + (row - 2560) * 1024 + col);
    else if (row < 2568) v = *(const float4*)(Wb + (row - 2564) * 1024 + col);
    else                 v = make_float4(0.f, 0.f, 0.f, 0.f);
    __hip_bfloat16 o[4] = { __float2bfloat16(v.x), __float2bfloat16(v.y),
                            __float2bfloat16(v.z), __float2bfloat16(v.w) };
    *(ushort4*)((unsigned short*)Wcat + idx) = *(ushort4*)o;
  }
}

// ---------------- bf16 MFMA GEMM: C(TOUT, MxN) = A(M,K) * B(N,K)^T ----------------
// 128x128 tile, 4 waves, 2-phase double-buffered LDS (round-10 config: plain
// 2D grid, no swizzle — measured best). TOUT = bf16 (proj) or f32 (final).
// If aux != nullptr, output columns [auxc0, auxc0+8) are ALSO stored f32 to
// aux[row*8 + (col-auxc0)] (keeps alpha/beta logits full-precision).
template <typename TOUT>
__global__ __launch_bounds__(256)
void gemm_bt_kernel(const __hip_bfloat16* __restrict__ A,
                    const __hip_bfloat16* __restrict__ Bw,
                    TOUT* __restrict__ C, int M, int N, int K,
                    float* __restrict__ aux, int auxc0)
{
  __shared__ __hip_bfloat16 As[2 * 128 * 32];
  __shared__ __hip_bfloat16 Bs[2 * 128 * 32];
  const int tid  = threadIdx.x;
  const int lane = tid & 63;
  const int w    = tid >> 6;
  const int wm   = w >> 1, wn = w & 1;
  const int tm   = blockIdx.x, tn = blockIdx.y;
  const int lr   = lane & 15, lk = lane >> 4;

  f32x4 acc[4][4] = {};

  const int e0   = tid * 8;
  const int srow = e0 >> 5;        // 0..63
  const int scol = e0 & 31;
  const __hip_bfloat16* Ap = A  + (size_t)(tm * 128 + srow) * K + scol;
  const __hip_bfloat16* Bp = Bw + (size_t)(tn * 128 + srow) * K + scol;
  char* AsB  = (char*)As;
  char* BsB  = (char*)Bs;
  const size_t half = (size_t)64 * K;
  const int nk = K >> 5;

  // prologue: stage K-tile 0 into buffer 0
  {
    char* AsD = AsB + w * 1024;
    char* BsD = BsB + w * 1024;
    gload_lds16(Ap,        AsD);
    gload_lds16(Ap + half, AsD + 4096);
    gload_lds16(Bp,        BsD);
    gload_lds16(Bp + half, BsD + 4096);
  }
  __syncthreads();

  for (int it = 0; it < nk; ++it) {
    const int sel = it & 1;
    // prefetch next K-tile into the other buffer (no wait here)
    if (it + 1 < nk) {
      const int kk = (it + 1) * 32;
      char* AsD = AsB + ((sel ^ 1) * 8192) + w * 1024;
      char* BsD = BsB + ((sel ^ 1) * 8192) + w * 1024;
      gload_lds16(Ap + kk,        AsD);
      gload_lds16(Ap + half + kk, AsD + 4096);
      gload_lds16(Bp + kk,        BsD);
      gload_lds16(Bp + half + kk, BsD + 4096);
    }
    // compute on current buffer
    const char* AsR = AsB + sel * 8192;
    const char* BsR = BsB + sel * 8192;
    bf16x8 af[4], bfv[4];
#pragma unroll
    for (int m = 0; m < 4; ++m)
      af[m]  = *(const bf16x8*)(AsR + ((wm * 64 + m * 16 + lr) * 32 + lk * 8) * 2);
#pragma unroll
    for (int n = 0; n < 4; ++n)
      bfv[n] = *(const bf16x8*)(BsR + ((wn * 64 + n * 16 + lr) * 32 + lk * 8) * 2);
#pragma unroll
    for (int m = 0; m < 4; ++m)
#pragma unroll
      for (int n = 0; n < 4; ++n)
        acc[m][n] = MFMA16(af[m], bfv[n], acc[m][n]);
    // barrier (drains vmcnt): next tile resident, current buffer reusable
    __syncthreads();
  }

  const int crow0 = tm * 128 + wm * 64 + (lane >> 4) * 4;
  const int ccol0 = tn * 128 + wn * 64 + lr;
#pragma unroll
  for (int m = 0; m < 4; ++m)
#pragma unroll
    for (int n = 0; n < 4; ++n) {
      const int cc = ccol0 + n * 16;
#pragma unroll
      for (int j = 0; j < 4; ++j) {
        const float v = acc[m][n][j];
        const size_t row = (size_t)(crow0 + m * 16 + j);
        if constexpr (sizeof(TOUT) == 2)
          ((unsigned short*)C)[row * N + cc] = (unsigned short)bf16s(v);
        else
          C[row * N + cc] = v;
        if (aux && cc >= auxc0 && cc < auxc0 + 8)
          aux[row * 8 + (cc - auxc0)] = v;
      }
    }
}

// ---------------- conv(4-tap causal) + silu + l2norm + sigmoid(a,b) ----------------
// Sliding-window over 8 timesteps per block (512 blocks). CBUF is bf16;
// alpha/beta logits come from the f32 side buffer abf. Outputs bf16.
__global__ __launch_bounds__(256)
void conv_act_kernel(const __hip_bfloat16* __restrict__ C, const float* __restrict__ abf,
                     const float* __restrict__ qcw, const float* __restrict__ qcb,
                     const float* __restrict__ kcw, const float* __restrict__ kcb,
                     const float* __restrict__ vcw, const float* __restrict__ vcb,
                     __hip_bfloat16* __restrict__ qh, __hip_bfloat16* __restrict__ kh,
                     __hip_bfloat16* __restrict__ vm, __hip_bfloat16* __restrict__ vg,
                     float* __restrict__ al, float* __restrict__ be)
{
  const int blk = blockIdx.x;           // 512
  const int bl0 = blk * 8;              // global row start (never crosses b: 2048%8==0)
  const int t0  = bl0 & (LQ - 1);       // local t start
  const int tid = threadIdx.x;
  const unsigned short* Cu = (const unsigned short*)C;
  __shared__ float red[4][16];

  float2 qv[8], kv[8];
  float sq[8], sk[8];
#pragma unroll
  for (int t = 0; t < 8; ++t) { sq[t] = 0.f; sk[t] = 0.f; }

  {
    const int c0 = tid * 2;
    const float4 wqA = *(const float4*)(qcw + 4 * c0);
    const float4 wqB = *(const float4*)(qcw + 4 * c0 + 4);
    const float4 wkA = *(const float4*)(kcw + 4 * c0);
    const float4 wkB = *(const float4*)(kcw + 4 * c0 + 4);
    const float2 bq = *(const float2*)(qcb + c0);
    const float2 bk = *(const float2*)(kcb + c0);
    float2 wrq[11], wrk[11];
#pragma unroll
    for (int r = 0; r < 11; ++r) {
      const int tt = t0 - 3 + r;
      if (tt >= 0) {
        const unsigned short* Cr = Cu + (size_t)(bl0 - 3 + r) * NPROJ;
        const ushort2 aq = *(const ushort2*)(Cr + c0);
        const ushort2 ak = *(const ushort2*)(Cr + 512 + c0);
        wrq[r] = make_float2(bfu2f(aq.x), bfu2f(aq.y));
        wrk[r] = make_float2(bfu2f(ak.x), bfu2f(ak.y));
      } else {
        wrq[r] = make_float2(0.f, 0.f);
        wrk[r] = make_float2(0.f, 0.f);
      }
    }
#pragma unroll
    for (int t = 0; t < 8; ++t) {
      float aq0 = bq.x, aq1 = bq.y, ak0 = bk.x, ak1 = bk.y;
#pragma unroll
      for (int j = 0; j < 4; ++j) {
        aq0 = fmaf(((const float*)&wqA)[j], wrq[t + j].x, aq0);
        aq1 = fmaf(((const float*)&wqB)[j], wrq[t + j].y, aq1);
        ak0 = fmaf(((const float*)&wkA)[j], wrk[t + j].x, ak0);
        ak1 = fmaf(((const float*)&wkB)[j], wrk[t + j].y, ak1);
      }
      const float q0 = siluf(aq0), q1 = siluf(aq1);
      const float k0 = siluf(ak0), k1 = siluf(ak1);
      qv[t] = make_float2(q0, q1);
      kv[t] = make_float2(k0, k1);
      sq[t] = fmaf(q1, q1, fmaf(q0, q0, sq[t]));
      sk[t] = fmaf(k1, k1, fmaf(k0, k0, sk[t]));
    }
  }
  // reduce sq,sk across 64 lanes, then across 4 waves
#pragma unroll
  for (int m = 1; m < 64; m <<= 1) {
#pragma unroll
    for (int t = 0; t < 8; ++t) {
      sq[t] += __shfl_xor(sq[t], m);
      sk[t] += __shfl_xor(sk[t], m);
    }
  }
  {
    const int w = tid >> 6, lane = tid & 63;
    if (lane == 0) {
#pragma unroll
      for (int t = 0; t < 8; ++t) { red[w][t] = sq[t]; red[w][8 + t] = sk[t]; }
    }
  }
  __syncthreads();
  float rnq[8], rnk[8];
#pragma unroll
  for (int t = 0; t < 8; ++t) {
    const float SQ = red[0][t] + red[1][t] + red[2][t] + red[3][t];
    const float SK = red[0][8 + t] + red[1][8 + t] + red[2][8 + t] + red[3][8 + t];
    rnq[t] = 1.f / fmaxf(sqrtf(SQ), 1e-12f);
    rnk[t] = 1.f / fmaxf(sqrtf(SK), 1e-12f);
  }
  {
    const int c0 = tid * 2;
#pragma unroll
    for (int t = 0; t < 8; ++t) {
      ushort2 oq, ok;
      oq.x = (unsigned short)bf16s(qv[t].x * rnq[t]);
      oq.y = (unsigned short)bf16s(qv[t].y * rnq[t]);
      ok.x = (unsigned short)bf16s(kv[t].x * rnk[t]);
      ok.y = (unsigned short)bf16s(kv[t].y * rnk[t]);
      *(ushort2*)((unsigned short*)qh + (size_t)(bl0 + t) * 512 + c0) = oq;
      *(ushort2*)((unsigned short*)kh + (size_t)(bl0 + t) * 512 + c0) = ok;
    }
  }
  // v: 4 consecutive channels per thread
  {
    const int cv = tid * 4;   // 0..1023
    const float4 wv0 = *(const float4*)(vcw + 4 * cv);
    const float4 wv1 = *(const float4*)(vcw + 4 * cv + 4);
    const float4 wv2 = *(const float4*)(vcw + 4 * cv + 8);
    const float4 wv3 = *(const float4*)(vcw + 4 * cv + 12);
    const float4 bv4 = *(const float4*)(vcb + cv);
    float4 wr[11];
#pragma unroll
    for (int r = 0; r < 11; ++r) {
      const int tt = t0 - 3 + r;
      if (tt >= 0) {
        const ushort4 u = *(const ushort4*)(Cu + (size_t)(bl0 - 3 + r) * NPROJ + 1024 + cv);
        wr[r] = make_float4(bfu2f(u.x), bfu2f(u.y), bfu2f(u.z), bfu2f(u.w));
      } else {
        wr[r] = make_float4(0.f, 0.f, 0.f, 0.f);
      }
    }
#pragma unroll
    for (int t = 0; t < 8; ++t) {
      float a0 = bv4.x, a1 = bv4.y, a2 = bv4.z, a3 = bv4.w;
#pragma unroll
      for (int j = 0; j < 4; ++j) {
        a0 = fmaf(((const float*)&wv0)[j], ((const float*)&wr[t + j])[0], a0);
        a1 = fmaf(((const float*)&wv1)[j], ((const float*)&wr[t + j])[1], a1);
        a2 = fmaf(((const float*)&wv2)[j], ((const float*)&wr[t + j])[2], a2);
        a3 = fmaf(((const float*)&wv3)[j], ((const float*)&wr[t + j])[3], a3);
      }
      ushort4 o;
      o.x = (unsigned short)bf16s(siluf(a0));
      o.y = (unsigned short)bf16s(siluf(a1));
      o.z = (unsigned short)bf16s(siluf(a2));
      o.w = (unsigned short)bf16s(siluf(a3));
      if (cv < 512) *(ushort4*)((unsigned short*)vm + (size_t)(bl0 + t) * 512 + cv)         = o;
      else          *(ushort4*)((unsigned short*)vg + (size_t)(bl0 + t) * 512 + (cv - 512)) = o;
    }
  }
  // alpha/beta from f32 side buffer: threads 0..63 cover 8 t x (4 al + 4 be)
  if (tid < 64) {
    const int t = tid >> 3;
    const int k = tid & 7;
    const float v = abf[(size_t)(bl0 + t) * 8 + k];
    if (k < 4) al[(size_t)(bl0 + t) * 4 + k]       = sigf(v);
    else       be[(size_t)(bl0 + t) * 4 + (k - 4)] = sigf(v);
  }
}

// ---------------- scan phase A (FUSED with transition), 512 threads ----------------
// 256 blocks = 32 chunks x 8 (b,h); 8 waves (2 waves/SIMD).
// Work split: G/Pq MFMA over 8 waves (t-band x s-half); substitution with TWO
// threads per column (A: rows 0-7 of each 16-block, B: rows 8-15, barrier
// handoff through the Xl spill); transition over 8 waves (row-band x col-qtr).
__global__ __launch_bounds__(512)
void scan_phaseA_kernel(const __hip_bfloat16* __restrict__ qh, const __hip_bfloat16* __restrict__ kh,
                        const __hip_bfloat16* __restrict__ vm, const float* __restrict__ al,
                        const float* __restrict__ be,
                        short* __restrict__ WTB, short* __restrict__ ZB,
                        short* __restrict__ PHB, float* __restrict__ GV,
                        short* __restrict__ TRB, float* __restrict__ BF)
{
  __shared__ char sm[136192];
  float* Xl = (float*)(sm);                             // [64][256] f32 (aliases KBl/QBl)
  __hip_bfloat16* KBl = (__hip_bfloat16*)(sm);          // [64][136]
  __hip_bfloat16* QBl = (__hip_bfloat16*)(sm + 17408);  // [64][136]
  float* Ll  = (float*)(sm + 65536);                    // [64][68]
  float* dv  = (float*)(sm + 82944);                    // [64]
  float* bv  = (float*)(sm + 83200);                    // [64]
  float* gbv = (float*)(sm + 83456);                    // [64]
  float* fvs = (float*)(sm + 83712);                    // [64]
  short* KTl  = (short*)(sm + 83968);                   // [128][68] bf16
  short* WTFl = (short*)(sm + 101376);                  // [128][68] bf16
  short* ZFl  = (short*)(sm + 118784);                  // [128][68] bf16

  const int cb = blockIdx.x;
  const int bh = cb & 7, c = cb >> 3;
  const int b = bh >> 2, h = bh & 3;
  const int tid = threadIdx.x;          // 0..511
  const int lane = tid & 63;
  const int w = tid >> 6;               // 0..7
  const int lr = lane & 15, lk = lane >> 4;
  const size_t rowbase = (size_t)(b * LQ + c * CT) * 512 + h * 128;

  // stage K,Q -> LDS bf16 (padded rows of 136); 2 reps of 512 threads
#pragma unroll
  for (int rep = 0; rep < 2; ++rep) {
    const int fid = tid + rep * 512;       // 0..1023
    const int r = fid >> 4;
    const int cg = (fid & 15) * 8;
    *(bf16x8*)(KBl + r * 136 + cg) = *(const bf16x8*)(kh + rowbase + (size_t)r * 512 + cg);
    *(bf16x8*)(QBl + r * 136 + cg) = *(const bf16x8*)(qh + rowbase + (size_t)r * 512 + cg);
  }
  // decay prefix (wave 0)
  if (w == 0) {
    float la = __logf(al[(size_t)(b * LQ + c * CT + lane) * 4 + h]);
    const float bb = be[(size_t)(b * LQ + c * CT + lane) * 4 + h];
#pragma unroll
    for (int off = 1; off < 64; off <<= 1) {
      const float tv = __shfl_up(la, off, 64);
      if (lane >= off) la += tv;
    }
    dv[lane] = la; bv[lane] = bb; gbv[lane] = bb * __expf(la);
    const float d63 = __shfl(la, 63, 64);
    fvs[lane] = __expf(d63 - la);
    GV[cb * 64 + lane] = __expf(la);
  }
  __syncthreads();

  // G = K K^T, Pq = Q K^T : wave w owns t-band (w&3) and s-half (w>>2)
  {
    const int tb = (w & 3) * 16;
    const int sh = (w >> 2) * 2;          // s-tile base (2 tiles per wave)
    f32x4 aG[2] = {}, aP[2] = {};
#pragma unroll
    for (int ks = 0; ks < 4; ++ks) {
      bf16x8 bk[2];
#pragma unroll
      for (int nt = 0; nt < 2; ++nt)
        bk[nt] = *(const bf16x8*)(KBl + ((sh + nt) * 16 + lr) * 136 + ks * 32 + lk * 8);
      const bf16x8 ak = *(const bf16x8*)(KBl + (tb + lr) * 136 + ks * 32 + lk * 8);
      const bf16x8 aq = *(const bf16x8*)(QBl + (tb + lr) * 136 + ks * 32 + lk * 8);
#pragma unroll
      for (int nt = 0; nt < 2; ++nt) {
        aG[nt] = MFMA16(ak, bk[nt], aG[nt]);
        aP[nt] = MFMA16(aq, bk[nt], aP[nt]);
      }
    }
#pragma unroll
    for (int nt = 0; nt < 2; ++nt)
#pragma unroll
      for (int jj = 0; jj < 4; ++jj) {
        const int t = tb + lk * 4 + jj;
        const int s = (sh + nt) * 16 + lr;
        const float eg = __expf(dv[t] - dv[s]);
        Ll[t * 68 + s] = (t > s) ? bv[t] * eg * aG[nt][jj] : 0.f;
        PHB[(size_t)cb * 4096 + t * 64 + s] = (s <= t) ? bf16s(eg * aP[nt][jj]) : (short)0;
      }
  }
  // KT (LDS) = K^T from staged KBl, BEFORE Xl overwrites it
  if (tid < 128) {
    const short* Kbs = (const short*)KBl;
#pragma unroll
    for (int s4 = 0; s4 < 16; ++s4) {
      s16x4 pk;
#pragma unroll
      for (int e = 0; e < 4; ++e)
        pk[e] = Kbs[(s4 * 4 + e) * 136 + tid];
      *(s16x4*)(KTl + tid * 68 + s4 * 4) = pk;
    }
  }
  __syncthreads();   // KBl/QBl dead from here -> Xl may overwrite

  // ---- blocked forward substitution: 2 threads per column ----
  const int j = tid & 255;
  const int half = tid >> 8;
  const int i0 = half * 8;
  const __hip_bfloat16* src = (j < 128) ? kh : vm;
  const __hip_bfloat16* xp = src + rowbase + (j & 127);
  float* XlC = Xl + j;                 // private column, stride 256 floats
  short* dstN = (j < 128) ? (WTB + (size_t)cb * 8192 + j)
                          : (ZB  + (size_t)cb * 8192 + (j - 128));
  short* dstT = (j < 128) ? (WTFl + j * 68)
                          : (ZFl  + (j - 128) * 68);

  for (int r = 0; r < 4; ++r) {
    float u[8];
#pragma unroll
    for (int i = 0; i < 8; ++i) {
      const int t = r * 16 + i0 + i;
      u[i] = __bfloat162float(xp[(size_t)t * 512]) * ((j < 128) ? gbv[t] : bv[t]);
    }
    for (int sc = 0; sc < r; ++sc) {
      float xs[16];
#pragma unroll
      for (int k = 0; k < 16; ++k) xs[k] = XlC[(sc * 16 + k) * 256];
#pragma unroll
      for (int i = 0; i < 8; ++i) {
        const float* lrow = Ll + (r * 16 + i0 + i) * 68 + sc * 16;
        const f32x4 l0 = *(const f32x4*)(lrow);
        const f32x4 l1 = *(const f32x4*)(lrow + 4);
        const f32x4 l2 = *(const f32x4*)(lrow + 8);
        const f32x4 l3 = *(const f32x4*)(lrow + 12);
        f32x4 acc = {};
        acc.x = fmaf(l0.x, xs[0],  acc.x); acc.y = fmaf(l0.y, xs[1],  acc.y);
        acc.z = fmaf(l0.z, xs[2],  acc.z); acc.w = fmaf(l0.w, xs[3],  acc.w);
        acc.x = fmaf(l1.x, xs[4],  acc.x); acc.y = fmaf(l1.y, xs[5],  acc.y);
        acc.z = fmaf(l1.z, xs[6],  acc.z); acc.w = fmaf(l1.w, xs[7],  acc.w);
        acc.x = fmaf(l2.x, xs[8],  acc.x); acc.y = fmaf(l2.y, xs[9],  acc.y);
        acc.z = fmaf(l2.z, xs[10], acc.z); acc.w = fmaf(l2.w, xs[11], acc.w);
        acc.x = fmaf(l3.x, xs[12], acc.x); acc.y = fmaf(l3.y, xs[13], acc.y);
        acc.z = fmaf(l3.z, xs[14], acc.z); acc.w = fmaf(l3.w, xs[15], acc.w);
        u[i] -= (acc.x + acc.y) + (acc.z + acc.w);
      }
    }
    if (half == 0) {
#pragma unroll
      for (int i = 1; i < 8; ++i) {
        const float* lrow = Ll + (r * 16 + i) * 68 + r * 16;
        f32x4 acc = {};
#pragma unroll
        for (int k4 = 0; k4 < 2; ++k4) {
          if (k4 * 4 < i) {
            const f32x4 lv = *(const f32x4*)(lrow + k4 * 4);
            acc.x = fmaf(lv.x, u[k4 * 4 + 0], acc.x);
            acc.y = fmaf(lv.y, u[k4 * 4 + 1], acc.y);
            acc.z = fmaf(lv.z, u[k4 * 4 + 2], acc.z);
            acc.w = fmaf(lv.w, u[k4 * 4 + 3], acc.w);
          }
        }
        u[i] -= (acc.x + acc.y) + (acc.z + acc.w);
      }
#pragma unroll
      for (int i = 0; i < 8; ++i) XlC[(r * 16 + i) * 256] = u[i];
#pragma unroll
      for (int i = 0; i < 8; ++i) dstN[(r * 16 + i) * 128] = bf16s(u[i]);
#pragma unroll
      for (int s4 = 0; s4 < 2; ++s4) {
        s16x4 p;
#pragma unroll
        for (int e = 0; e < 4; ++e)
          p[e] = bf16s(fvs[r * 16 + s4 * 4 + e] * u[s4 * 4 + e]);
        *(s16x4*)(dstT + r * 16 + s4 * 4) = p;
      }
    }
    __syncthreads();   // A-half spill visible
    if (half == 1) {
      float xa[8];
#pragma unroll
      for (int k = 0; k < 8; ++k) xa[k] = XlC[(r * 16 + k) * 256];
#pragma unroll
      for (int i = 0; i < 8; ++i) {
        const float* lrow = Ll + (r * 16 + 8 + i) * 68 + r * 16;
        const f32x4 l0 = *(const f32x4*)(lrow);
        const f32x4 l1 = *(const f32x4*)(lrow + 4);
        f32x4 acc = {};
        acc.x = fmaf(l0.x, xa[0], acc.x); acc.y = fmaf(l0.y, xa[1], acc.y);
        acc.z = fmaf(l0.z, xa[2], acc.z); acc.w = fmaf(l0.w, xa[3], acc.w);
        acc.x = fmaf(l1.x, xa[4], acc.x); acc.y = fmaf(l1.y, xa[5], acc.y);
        acc.z = fmaf(l1.z, xa[6], acc.z); acc.w = fmaf(l1.w, xa[7], acc.w);
        u[i] -= (acc.x + acc.y) + (acc.z + acc.w);
      }
#pragma unroll
      for (int i = 1; i < 8; ++i) {
        const float* lrow = Ll + (r * 16 + 8 + i) * 68 + r * 16 + 8;
        f32x4 acc = {};
#pragma unroll
        for (int k4 = 0; k4 < 2; ++k4) {
          if (k4 * 4 < i) {
            const f32x4 lv = *(const f32x4*)(lrow + k4 * 4);
            acc.x = fmaf(lv.x, u[k4 * 4 + 0], acc.x);
            acc.y = fmaf(lv.y, u[k4 * 4 + 1], acc.y);
            acc.z = fmaf(lv.z, u[k4 * 4 + 2], acc.z);
            acc.w = fmaf(lv.w, u[k4 * 4 + 3], acc.w);
          }
        }
        u[i] -= (acc.x + acc.y) + (acc.z + acc.w);
      }
#pragma unroll
      for (int i = 0; i < 8; ++i) XlC[(r * 16 + 8 + i) * 256] = u[i];
#pragma unroll
      for (int i = 0; i < 8; ++i) dstN[(r * 16 + 8 + i) * 128] = bf16s(u[i]);
#pragma unroll
      for (int s4 = 0; s4 < 2; ++s4) {
        s16x4 p;
#pragma unroll
        for (int e = 0; e < 4; ++e)
          p[e] = bf16s(fvs[r * 16 + 8 + s4 * 4 + e] * u[s4 * 4 + e]);
        *(s16x4*)(dstT + r * 16 + 8 + s4 * 4) = p;
      }
    }
    __syncthreads();   // block r fully solved
  }

  // ---- fused transition: 8 waves, wave w owns row-band (w&3) x col-quarter (w>>2)
  const float gc = __expf(dv[63]);
  const int rb = (w & 3) * 32;
  const int cq = (w >> 2) * 4;
  {
    f32x4 acc[2][4] = {};
#pragma unroll
    for (int ks = 0; ks < 2; ++ks) {
      const bf16x8 a0 = *(const bf16x8*)(KTl + (rb + lr) * 68 + ks * 32 + lk * 8);
      const bf16x8 a1 = *(const bf16x8*)(KTl + (rb + 16 + lr) * 68 + ks * 32 + lk * 8);
#pragma unroll
      for (int nt = 0; nt < 4; ++nt) {
        const bf16x8 bm = *(const bf16x8*)(WTFl + ((cq + nt) * 16 + lr) * 68 + ks * 32 + lk * 8);
        acc[0][nt] = MFMA16(a0, bm, acc[0][nt]);
        acc[1][nt] = MFMA16(a1, bm, acc[1][nt]);
      }
    }
#pragma unroll
    for (int mt = 0; mt < 2; ++mt)
#pragma unroll
      for (int nt = 0; nt < 4; ++nt)
#pragma unroll
        for (int jj = 0; jj < 4; ++jj) {
          const int jr = rb + mt * 16 + lk * 4 + jj;
          const int m  = (cq + nt) * 16 + lr;
          const float v = ((jr == m) ? gc : 0.f) - acc[mt][nt][jj];
          TRB[(size_t)cb * 16384 + jr * 128 + m] = bf16s(v);
        }
  }
  {
    f32x4 acc[2][4] = {};
#pragma unroll
    for (int ks = 0; ks < 2; ++ks) {
      const bf16x8 a0 = *(const bf16x8*)(ZFl + (rb + lr) * 68 + ks * 32 + lk * 8);
      const bf16x8 a1 = *(const bf16x8*)(ZFl + (rb + 16 + lr) * 68 + ks * 32 + lk * 8);
#pragma unroll
      for (int nt = 0; nt < 4; ++nt) {
        const bf16x8 bj = *(const bf16x8*)(KTl + ((cq + nt) * 16 + lr) * 68 + ks * 32 + lk * 8);
        acc[0][nt] = MFMA16(a0, bj, acc[0][nt]);
        acc[1][nt] = MFMA16(a1, bj, acc[1][nt]);
      }
    }
#pragma unroll
    for (int mt = 0; mt < 2; ++mt)
#pragma unroll
      for (int nt = 0; nt < 4; ++nt)
#pragma unroll
        for (int jj = 0; jj < 4; ++jj) {
          const int ir = rb + mt * 16 + lk * 4 + jj;
          const int jc = (cq + nt) * 16 + lr;
          BF[(size_t)cb * 16384 + ir * 128 + jc] = acc[mt][nt][jj];
        }
  }
}

// ---------------- scan state: serial chunk recurrence, S rows independent ----
#define L2_PREFETCH(BT, BA, CC) do {                                               \
  const int cbn_ = (CC) * 8 + bh;                                                  \
  _Pragma("unroll") for (int nt = 0; nt < 2; ++nt) {                               \
    _Pragma("unroll") for (int ks = 0; ks < 4; ++ks)                               \
      BT[nt][ks] = *(const bf16x8*)(TRB + (size_t)cbn_ * 16384 +                   \
                                    (w * 32 + nt * 16 + lr) * 128 + ks * 32 + lk * 8); \
    _Pragma("unroll") for (int jj = 0; jj < 4; ++jj)                               \
      BA[nt][jj] = BF[(size_t)cbn_ * 16384 + (r0 + lk * 4 + jj) * 128 +            \
                      w * 32 + nt * 16 + lr];                                      \
  }                                                                                \
} while (0)

#define L2_STEP(BT, BA, CC, PBT, PBA) do {                                         \
  const int cb_ = (CC) * 8 + bh;                                                   \
  { const int idx = tid * 8, r = idx >> 7, jc = idx & 127;                         \
    f32x4 s0 = *(const f32x4*)&Scur[r * 132 + jc];                                 \
    f32x4 s1 = *(const f32x4*)&Scur[r * 132 + jc + 4];                             \
    *(bf16x8*)(SALL + (size_t)cb_ * 16384 + (r0 + r) * 128 + jc) = pack8(s0, s1); }\
  bf16x8 af[4];                                                                    \
  _Pragma("unroll") for (int ks = 0; ks < 4; ++ks)                                 \
    af[ks] = pack8(*(const f32x4*)&Scur[lr * 132 + ks * 32 + lk * 8],              \
                   *(const f32x4*)&Scur[lr * 132 + ks * 32 + lk * 8 + 4]);         \
  if ((CC) < 31) L2_PREFETCH(PBT, PBA, (CC) + 1);                                  \
  f32x4 acc0 = {}, acc1 = {};                                                      \
  _Pragma("unroll") for (int ks = 0; ks < 4; ++ks) {                               \
    acc0 = MFMA16(af[ks], BT[0][ks], acc0);                                        \
    acc1 = MFMA16(af[ks], BT[1][ks], acc1);                                        \
  }                                                                                \
  _Pragma("unroll") for (int jj = 0; jj < 4; ++jj) {                               \
    Snxt[(lk * 4 + jj) * 132 + w * 32 + lr]      = acc0[jj] + BA[0][jj];           \
    Snxt[(lk * 4 + jj) * 132 + w * 32 + 16 + lr] = acc1[jj] + BA[1][jj];           \
  }                                                                                \
  __syncthreads();                                                                 \
  { float* t_ = Scur; Scur = Snxt; Snxt = t_; }                                    \
} while (0)

__global__ __launch_bounds__(256)
void scan_state_kernel(const short* __restrict__ TRB, const float* __restrict__ BF,
                       const float* __restrict__ st0, short* __restrict__ SALL,
                       float* __restrict__ stout)
{
  __shared__ float Sl[2 * 16 * 132];
  const int bid = blockIdx.x;            // 64
  const int bh = bid & 7, slab = bid >> 3;
  const int r0 = slab * 16;
  const int tid = threadIdx.x, lane = tid & 63, w = tid >> 6;
  const int lr = lane & 15, lk = lane >> 4;

  float* Scur = Sl;
  float* Snxt = Sl + 16 * 132;

  {
    const int idx = tid * 8, r = idx >> 7, jc = idx & 127;
    const float* sp = st0 + ((size_t)bh * 128 + r0 + r) * 128 + jc;
    *(f32x4*)&Scur[r * 132 + jc]     = *(const f32x4*)sp;
    *(f32x4*)&Scur[r * 132 + jc + 4] = *(const f32x4*)(sp + 4);
  }
  bf16x8 btA[2][4], btB[2][4];
  float  baA[2][4], baB[2][4];
  L2_PREFETCH(btA, baA, 0);
  __syncthreads();

  for (int c2 = 0; c2 < 16; ++c2) {
    L2_STEP(btA, baA, 2 * c2,     btB, baB);
    L2_STEP(btB, baB, 2 * c2 + 1, btA, baA);
  }

  {
    const int idx = tid * 8, r = idx >> 7, jc = idx & 127;
    float* sp = stout + ((size_t)bh * 128 + r0 + r) * 128 + jc;
    *(f32x4*)sp       = *(const f32x4*)&Scur[r * 132 + jc];
    *(f32x4*)(sp + 4) = *(const f32x4*)&Scur[r * 132 + jc + 4];
  }
}

// ---------------- scan output: fully parallel over chunks ----------------
__global__ __launch_bounds__(512)
void scan_output_kernel(const __hip_bfloat16* __restrict__ qh,
                        const short* __restrict__ WTB, const __hip_bfloat16* __restrict__ ZB,
                        const short* __restrict__ PHB, const float* __restrict__ GV,
                        const short* __restrict__ SALL, __hip_bfloat16* __restrict__ obuf)
{
  __shared__ short Ut[128 * 72];
  const int cb = blockIdx.x;
  const int bh = cb & 7, c = cb >> 3;
  const int b = bh >> 2, h = bh & 3;
  const int tid = threadIdx.x, lane = tid & 63, w = tid >> 6;   // w 0..7
  const int lr = lane & 15, lk = lane >> 4;
  const int r0 = (w & 3) * 16;

  f32x4 Y[8] = {};
#pragma unroll
  for (int ks = 0; ks < 4; ++ks) {
    bf16x8 af;
    if (w < 4) {
      af = *(const bf16x8*)(qh + ((size_t)(b * LQ + c * CT) + r0 + lr) * 512 + h * 128 + ks * 32 + lk * 8);
    } else {
      af = *(const bf16x8*)(WTB + (size_t)cb * 8192 + (r0 + lr) * 128 + ks * 32 + lk * 8);
    }
#pragma unroll
    for (int nt = 0; nt < 8; ++nt) {
      const bf16x8 bs = *(const bf16x8*)(SALL + (size_t)cb * 16384 + (nt * 16 + lr) * 128 + ks * 32 + lk * 8);
      Y[nt] = MFMA16(af, bs, Y[nt]);
    }
  }
  if (w >= 4) {   // U = Z - Y_low -> LDS (Ut[i][s])
#pragma unroll
    for (int nt = 0; nt < 8; ++nt) {
      const int i = nt * 16 + lr;
      s16x4 up;
#pragma unroll
      for (int jj = 0; jj < 4; ++jj) {
        const int s = r0 + lk * 4 + jj;
        const float z = __bfloat162float(ZB[(size_t)cb * 8192 + s * 128 + i]);
        up[jj] = bf16s(z - Y[nt][jj]);
      }
      *(s16x4*)&Ut[i * 72 + r0 + lk * 4] = up;
    }
  }
  __syncthreads();
  if (w < 4) {
    f32x4 P2[8] = {};
#pragma unroll
    for (int ks = 0; ks < 2; ++ks) {
      const bf16x8 ap = *(const bf16x8*)(PHB + (size_t)cb * 4096 + (r0 + lr) * 64 + ks * 32 + lk * 8);
#pragma unroll
      for (int nt = 0; nt < 8; ++nt) {
        const bf16x8 bu = *(const bf16x8*)&Ut[(nt * 16 + lr) * 72 + ks * 32 + lk * 8];
        P2[nt] = MFMA16(ap, bu, P2[nt]);
      }
    }
    float gvv[4];
#pragma unroll
    for (int jj = 0; jj < 4; ++jj) gvv[jj] = GV[cb * 64 + r0 + lk * 4 + jj];
#pragma unroll
    for (int nt = 0; nt < 8; ++nt) {
      const int i = nt * 16 + lr;
#pragma unroll
      for (int jj = 0; jj < 4; ++jj) {
        const int t = r0 + lk * 4 + jj;
        ((unsigned short*)obuf)[((size_t)(b * LQ + c * CT) + t) * 512 + h * 128 + i] =
            (unsigned short)bf16s(gvv[jj] * Y[nt][jj] + P2[nt][jj]);
      }
    }
  }
}

// ---------------- gate * silu(g), LayerNorm(512), cast bf16 ----------------
// Batched 8 rows per block (512 blocks): amortizes barrier + block ramp 8x.
// Per-row reduction order identical to the 1-row version (bit-identical).
__global__ __launch_bounds__(256)
void gate_ln_kernel(const __hip_bfloat16* __restrict__ obuf, const __hip_bfloat16* __restrict__ vg,
                    const __hip_bfloat16* __restrict__ C, const float* __restrict__ lnw,
                    const float* __restrict__ lnb, __hip_bfloat16* __restrict__ lno)
{
  const int bl0 = blockIdx.x * 8;
  const int tid = threadIdx.x;
  const int c0 = tid * 2;
  __shared__ float red[4][16];
  float y0[8], y1[8];
  float s[8], s2[8];
#pragma unroll
  for (int t = 0; t < 8; ++t) {
    const size_t bl = bl0 + t;
    const ushort2 ovu = *(const ushort2*)((const unsigned short*)obuf + bl * 512 + c0);
    const ushort2 gvu = *(const ushort2*)((const unsigned short*)vg + bl * 512 + c0);
    const ushort2 ggu = *(const ushort2*)((const unsigned short*)C + bl * NPROJ + 2048 + c0);
    const float v0 = bfu2f(ovu.x) * bfu2f(gvu.x) * siluf(bfu2f(ggu.x));
    const float v1 = bfu2f(ovu.y) * bfu2f(gvu.y) * siluf(bfu2f(ggu.y));
    y0[t] = v0; y1[t] = v1;
    s[t] = v0 + v1;
    s2[t] = fmaf(v1, v1, v0 * v0);
  }
#pragma unroll
  for (int m = 1; m < 64; m <<= 1) {
#pragma unroll
    for (int t = 0; t < 8; ++t) {
      s[t]  += __shfl_xor(s[t],  m);
      s2[t] += __shfl_xor(s2[t], m);
    }
  }
  {
    const int w = tid >> 6, lane = tid & 63;
    if (lane == 0) {
#pragma unroll
      for (int t = 0; t < 8; ++t) { red[w][t] = s[t]; red[w][8 + t] = s2[t]; }
    }
  }
  __syncthreads();
  const float2 lw = *(const float2*)(lnw + c0);
  const float2 lb = *(const float2*)(lnb + c0);
#pragma unroll
  for (int t = 0; t < 8; ++t) {
    const float S  = red[0][t] + red[1][t] + red[2][t] + red[3][t];
    const float S2 = red[0][8 + t] + red[1][8 + t] + red[2][8 + t] + red[3][8 + t];
    const float mu  = S * (1.f / 512.f);
    const float var = S2 * (1.f / 512.f) - mu * mu;
    const float rs  = rsqrtf(var + 1e-5f);
    __hip_bfloat16 o[2] = {
      __float2bfloat16(fmaf((y0[t] - mu) * rs, lw.x, lb.x)),
      __float2bfloat16(fmaf((y1[t] - mu) * rs, lw.y, lb.y)) };
    *(ushort2*)((unsigned short*)lno + (size_t)(bl0 + t) * 512 + c0) = *(ushort2*)o;
  }
}

extern "C" void kernel_launch(void* const* d_in, const int* in_sizes, int n_in,
                              void* d_out, int out_size, void* d_ws, size_t ws_size,
                              hipStream_t stream)
{
  (void)in_sizes; (void)n_in; (void)out_size; (void)ws_size;
  const float* x    = (const float*)d_in[0];
  const float* st0  = (const float*)d_in[1];
  const float* Wq   = (const float*)d_in[2];
  const float* Wk   = (const float*)d_in[3];
  const float* Wv   = (const float*)d_in[4];
  const float* Wa   = (const float*)d_in[5];
  const float* Wb   = (const float*)d_in[6];
  const float* Wg   = (const float*)d_in[7];
  const float* Wo   = (const float*)d_in[8];
  const float* qcw  = (const float*)d_in[9];
  const float* qcb  = (const float*)d_in[10];
  const float* kcw  = (const float*)d_in[11];
  const float* kcb  = (const float*)d_in[12];
  const float* vcw  = (const float*)d_in[13];
  const float* vcb  = (const float*)d_in[14];
  const float* lnw  = (const float*)d_in[15];
  const float* lnb  = (const float*)d_in[16];
  float* out = (float*)d_out;

  // workspace layout (bytes); high-water ~141.2 MB
  char* ws = (char*)d_ws;
  __hip_bfloat16* XB   = (__hip_bfloat16*)(ws + 0);            // 4096x1024 bf16 (dead after proj GEMM)
  __hip_bfloat16* LNO  = (__hip_bfloat16*)(ws + 0);            // 4096x512 bf16 (aliases XB 1st half)
  short*          WTB  = (short*)(ws + 4194304);               // [256][64][128] bf16 (aliases XB 2nd half)
  __hip_bfloat16* WCAT = (__hip_bfloat16*)(ws + 8388608);      // 2688x1024 bf16
  __hip_bfloat16* WOB  = (__hip_bfloat16*)(ws + 13893632);     // 1024x512  bf16
  __hip_bfloat16* CBUFH = (__hip_bfloat16*)(ws + 14942208);    // 4096x2688 bf16
  __hip_bfloat16* QH   = (__hip_bfloat16*)(ws + 58982400);     // 4096x512 bf16
  __hip_bfloat16* KH   = (__hip_bfloat16*)(ws + 67371008);     // 4096x512 bf16
  __hip_bfloat16* VM   = (__hip_bfloat16*)(ws + 75759616);     // 4096x512 bf16
  __hip_bfloat16* VG   = (__hip_bfloat16*)(ws + 84148224);     // 4096x512 bf16
  float* AL   = (float*)(ws + 92536832);                       // 4096x4
  float* BE   = (float*)(ws + 92602368);
  __hip_bfloat16* OBUF = (__hip_bfloat16*)(ws + 92667904);     // 4096x512 bf16 (written by scan_output)
  short* TRB  = (short*)(ws + 92667904);                       // [256][128][128] bf16 (aliases OBUF; dead before scan_output)
  short* PHB  = (short*)(ws + 105250816);                      // [256][64][64] bf16
  short* ZB   = (short*)(ws + 107347968);                      // [256][64][128] bf16
  float* GV   = (float*)(ws + 111542272);                      // [256][64]
  short* SALL = (short*)(ws + 115868672);                      // [256][128][128] bf16 chunk-start states
  float* ABF  = (float*)(ws + 124257280);                      // [4096][8] f32 alpha/beta logits
  float* BF   = (float*)(ws + 124388352);                      // [256][128][128] f32 (fresh region; no aliasing)

  cast_all_kernel<<<7296, 256, 0, stream>>>(x, Wo, Wq, Wk, Wv, Wg, Wa, Wb, XB, WOB, WCAT);

  gemm_bt_kernel<__hip_bfloat16><<<dim3(32, 21), 256, 0, stream>>>(
      XB, WCAT, CBUFH, BLQ, NPROJ, KPROJ, ABF, 2560);

  conv_act_kernel<<<512, 256, 0, stream>>>(CBUFH, ABF, qcw, qcb, kcw, kcb, vcw, vcb,
                                           QH, KH, VM, VG, AL, BE);

  scan_phaseA_kernel<<<256, 512, 0, stream>>>(QH, KH, VM, AL, BE,
                                              WTB, ZB, PHB, GV, TRB, BF);

  scan_state_kernel<<<64, 256, 0, stream>>>(TRB, BF, st0, SALL, out + 4194304);

  scan_output_kernel<<<256, 512, 0, stream>>>(QH, WTB, (const __hip_bfloat16*)ZB,
                                              PHB, GV, SALL, OBUF);

  gate_ln_kernel<<<512, 256, 0, stream>>>(OBUF, VG, CBUFH, lnw, lnb, LNO);

  gemm_bt_kernel<float><<<dim3(32, 8), 256, 0, stream>>>(
      LNO, WOB, out, BLQ, DMQ, TOTQ, nullptr, 0);
}

// Round 15
// 143.477 us; speedup vs baseline: 1.0429x; 1.0132x over previous
//
#include <hip/hip_runtime.h>
#include <hip/hip_bf16.h>

// Problem constants
#define BQ    2
#define LQ    2048
#define DMQ   1024
#define HQ    4
#define DHQ   128
#define TOTQ  512
#define BLQ   4096      // B*L
#define NPROJ 2688      // padded concat: Wq(512) Wk(512) Wv(1024) Wg(512) Wa(4) Wb(4) pad(120)
#define KPROJ 1024
#define CT    64        // scan chunk length
#define NCH   32        // chunks (LQ/CT)

typedef short bf16x8 __attribute__((ext_vector_type(8)));
typedef short s16x4  __attribute__((ext_vector_type(4)));
typedef float f32x4  __attribute__((ext_vector_type(4)));

#define MFMA16(a, b, c) __builtin_amdgcn_mfma_f32_16x16x32_bf16(a, b, c, 0, 0, 0)

__device__ __forceinline__ float siluf(float x) { return x / (1.f + __expf(-x)); }
__device__ __forceinline__ float sigf(float x)  { return 1.f / (1.f + __expf(-x)); }
__device__ __forceinline__ short bf16s(float x) {
  return __builtin_bit_cast(short, __float2bfloat16(x));
}
__device__ __forceinline__ float bfu2f(unsigned short u) {
  return __bfloat162float(__builtin_bit_cast(__hip_bfloat16, u));
}
__device__ __forceinline__ bf16x8 pack8(f32x4 a, f32x4 b) {
  bf16x8 r;
  r[0] = bf16s(a.x); r[1] = bf16s(a.y); r[2] = bf16s(a.z); r[3] = bf16s(a.w);
  r[4] = bf16s(b.x); r[5] = bf16s(b.y); r[6] = bf16s(b.z); r[7] = bf16s(b.w);
  return r;
}

// global -> LDS direct load, 16B per lane. LDS dest must be wave-uniform base;
// HW writes base + lane*16.
__device__ __forceinline__ void gload_lds16(const void* g, void* l) {
  __builtin_amdgcn_global_load_lds(
      (__attribute__((address_space(1))) void*)(unsigned long long)g,
      (__attribute__((address_space(3))) void*)(unsigned int)(unsigned long long)l,
      16, 0, 0);
}

// ---------------- merged casts: x->XB, Wo->WOB, Wcat (one launch) ----------------
__global__ __launch_bounds__(256)
void cast_all_kernel(const float* __restrict__ x, const float* __restrict__ Wo,
                     const float* __restrict__ Wq, const float* __restrict__ Wk,
                     const float* __restrict__ Wv, const float* __restrict__ Wg,
                     const float* __restrict__ Wa, const float* __restrict__ Wb,
                     __hip_bfloat16* __restrict__ XB, __hip_bfloat16* __restrict__ WOB,
                     __hip_bfloat16* __restrict__ Wcat)
{
  const int bid = blockIdx.x;
  const int tid = threadIdx.x;
  if (bid < 4096) {                      // x: 4096x1024 f32, 4/thread
    const int i = bid * 256 + tid;
    float4 v = ((const float4*)x)[i];
    __hip_bfloat16 o[4] = { __float2bfloat16(v.x), __float2bfloat16(v.y),
                            __float2bfloat16(v.z), __float2bfloat16(v.w) };
    *(ushort4*)((unsigned short*)XB + (size_t)i * 4) = *(ushort4*)o;
  } else if (bid < 4608) {               // Wo: 1024x512 f32
    const int i = (bid - 4096) * 256 + tid;
    float4 v = ((const float4*)Wo)[i];
    __hip_bfloat16 o[4] = { __float2bfloat16(v.x), __float2bfloat16(v.y),
                            __float2bfloat16(v.z), __float2bfloat16(v.w) };
    *(ushort4*)((unsigned short*)WOB + (size_t)i * 4) = *(ushort4*)o;
  } else {                               // Wcat: 2688 rows x 1024
    const int i4 = (bid - 4608) * 256 + tid;
    const int row = i4 >> 8;
    const int col = (i4 & 255) * 4;
    const int idx = row * 1024 + col;
    float4 v;
    if      (row < 512)  v = *(const float4*)(Wq + idx);
    else if (row < 1024) v = *(const float4*)(Wk + idx - 512 * 1024);
    else if (row < 2048) v = *(const float4*)(Wv + idx - 1024 * 1024);
    else if (row < 2560) v = *(const float4*)(Wg + idx - 2048 * 1024);
    else if (row < 2564) v = *(const float4*)(Wa + (row - 2560) * 1024 + col);
    else if (row < 2568) v = *(const float4*)(Wb + (row - 2564) * 1024 + col);
    else                 v = make_float4(0.f, 0.f, 0.f, 0.f);
    __hip_bfloat16 o[4] = { __float2bfloat16(v.x), __float2bfloat16(v.y),
                            __float2bfloat16(v.z), __float2bfloat16(v.w) };
    *(ushort4*)((unsigned short*)Wcat + idx) = *(ushort4*)o;
  }
}

// ---------------- bf16 MFMA GEMM: C(TOUT, MxN) = A(M,K) * B(N,K)^T ----------------
// 128x128 tile, 4 waves, 2-phase double-buffered LDS, plain 2D grid (measured
// best configuration). TOUT = bf16 (proj) or f32 (final).
// If aux != nullptr, output columns [auxc0, auxc0+8) are ALSO stored f32 to
// aux[row*8 + (col-auxc0)] (keeps alpha/beta logits full-precision).
template <typename TOUT>
__global__ __launch_bounds__(256)
void gemm_bt_kernel(const __hip_bfloat16* __restrict__ A,
                    const __hip_bfloat16* __restrict__ Bw,
                    TOUT* __restrict__ C, int M, int N, int K,
                    float* __restrict__ aux, int auxc0)
{
  __shared__ __hip_bfloat16 As[2 * 128 * 32];
  __shared__ __hip_bfloat16 Bs[2 * 128 * 32];
  const int tid  = threadIdx.x;
  const int lane = tid & 63;
  const int w    = tid >> 6;
  const int wm   = w >> 1, wn = w & 1;
  const int tm   = blockIdx.x, tn = blockIdx.y;
  const int lr   = lane & 15, lk = lane >> 4;

  f32x4 acc[4][4] = {};

  const int e0   = tid * 8;
  const int srow = e0 >> 5;        // 0..63
  const int scol = e0 & 31;
  const __hip_bfloat16* Ap = A  + (size_t)(tm * 128 + srow) * K + scol;
  const __hip_bfloat16* Bp = Bw + (size_t)(tn * 128 + srow) * K + scol;
  char* AsB  = (char*)As;
  char* BsB  = (char*)Bs;
  const size_t half = (size_t)64 * K;
  const int nk = K >> 5;

  // prologue: stage K-tile 0 into buffer 0
  {
    char* AsD = AsB + w * 1024;
    char* BsD = BsB + w * 1024;
    gload_lds16(Ap,        AsD);
    gload_lds16(Ap + half, AsD + 4096);
    gload_lds16(Bp,        BsD);
    gload_lds16(Bp + half, BsD + 4096);
  }
  __syncthreads();

  for (int it = 0; it < nk; ++it) {
    const int sel = it & 1;
    // prefetch next K-tile into the other buffer (no wait here)
    if (it + 1 < nk) {
      const int kk = (it + 1) * 32;
      char* AsD = AsB + ((sel ^ 1) * 8192) + w * 1024;
      char* BsD = BsB + ((sel ^ 1) * 8192) + w * 1024;
      gload_lds16(Ap + kk,        AsD);
      gload_lds16(Ap + half + kk, AsD + 4096);
      gload_lds16(Bp + kk,        BsD);
      gload_lds16(Bp + half + kk, BsD + 4096);
    }
    // compute on current buffer
    const char* AsR = AsB + sel * 8192;
    const char* BsR = BsB + sel * 8192;
    bf16x8 af[4], bfv[4];
#pragma unroll
    for (int m = 0; m < 4; ++m)
      af[m]  = *(const bf16x8*)(AsR + ((wm * 64 + m * 16 + lr) * 32 + lk * 8) * 2);
#pragma unroll
    for (int n = 0; n < 4; ++n)
      bfv[n] = *(const bf16x8*)(BsR + ((wn * 64 + n * 16 + lr) * 32 + lk * 8) * 2);
#pragma unroll
    for (int m = 0; m < 4; ++m)
#pragma unroll
      for (int n = 0; n < 4; ++n)
        acc[m][n] = MFMA16(af[m], bfv[n], acc[m][n]);
    // barrier (drains vmcnt): next tile resident, current buffer reusable
    __syncthreads();
  }

  const int crow0 = tm * 128 + wm * 64 + (lane >> 4) * 4;
  const int ccol0 = tn * 128 + wn * 64 + lr;
#pragma unroll
  for (int m = 0; m < 4; ++m)
#pragma unroll
    for (int n = 0; n < 4; ++n) {
      const int cc = ccol0 + n * 16;
#pragma unroll
      for (int j = 0; j < 4; ++j) {
        const float v = acc[m][n][j];
        const size_t row = (size_t)(crow0 + m * 16 + j);
        if constexpr (sizeof(TOUT) == 2)
          ((unsigned short*)C)[row * N + cc] = (unsigned short)bf16s(v);
        else
          C[row * N + cc] = v;
        if (aux && cc >= auxc0 && cc < auxc0 + 8)
          aux[row * 8 + (cc - auxc0)] = v;
      }
    }
}

// ---------------- conv(4-tap causal) + silu + l2norm + sigmoid(a,b) ----------------
// Sliding-window over 8 timesteps per block (512 blocks). CBUF is bf16;
// alpha/beta logits come from the f32 side buffer abf. Outputs bf16.
__global__ __launch_bounds__(256)
void conv_act_kernel(const __hip_bfloat16* __restrict__ C, const float* __restrict__ abf,
                     const float* __restrict__ qcw, const float* __restrict__ qcb,
                     const float* __restrict__ kcw, const float* __restrict__ kcb,
                     const float* __restrict__ vcw, const float* __restrict__ vcb,
                     __hip_bfloat16* __restrict__ qh, __hip_bfloat16* __restrict__ kh,
                     __hip_bfloat16* __restrict__ vm, __hip_bfloat16* __restrict__ vg,
                     float* __restrict__ al, float* __restrict__ be)
{
  const int blk = blockIdx.x;           // 512
  const int bl0 = blk * 8;              // global row start (never crosses b: 2048%8==0)
  const int t0  = bl0 & (LQ - 1);       // local t start
  const int tid = threadIdx.x;
  const unsigned short* Cu = (const unsigned short*)C;
  __shared__ float red[4][16];

  float2 qv[8], kv[8];
  float sq[8], sk[8];
#pragma unroll
  for (int t = 0; t < 8; ++t) { sq[t] = 0.f; sk[t] = 0.f; }

  {
    const int c0 = tid * 2;
    const float4 wqA = *(const float4*)(qcw + 4 * c0);
    const float4 wqB = *(const float4*)(qcw + 4 * c0 + 4);
    const float4 wkA = *(const float4*)(kcw + 4 * c0);
    const float4 wkB = *(const float4*)(kcw + 4 * c0 + 4);
    const float2 bq = *(const float2*)(qcb + c0);
    const float2 bk = *(const float2*)(kcb + c0);
    float2 wrq[11], wrk[11];
#pragma unroll
    for (int r = 0; r < 11; ++r) {
      const int tt = t0 - 3 + r;
      if (tt >= 0) {
        const unsigned short* Cr = Cu + (size_t)(bl0 - 3 + r) * NPROJ;
        const ushort2 aq = *(const ushort2*)(Cr + c0);
        const ushort2 ak = *(const ushort2*)(Cr + 512 + c0);
        wrq[r] = make_float2(bfu2f(aq.x), bfu2f(aq.y));
        wrk[r] = make_float2(bfu2f(ak.x), bfu2f(ak.y));
      } else {
        wrq[r] = make_float2(0.f, 0.f);
        wrk[r] = make_float2(0.f, 0.f);
      }
    }
#pragma unroll
    for (int t = 0; t < 8; ++t) {
      float aq0 = bq.x, aq1 = bq.y, ak0 = bk.x, ak1 = bk.y;
#pragma unroll
      for (int j = 0; j < 4; ++j) {
        aq0 = fmaf(((const float*)&wqA)[j], wrq[t + j].x, aq0);
        aq1 = fmaf(((const float*)&wqB)[j], wrq[t + j].y, aq1);
        ak0 = fmaf(((const float*)&wkA)[j], wrk[t + j].x, ak0);
        ak1 = fmaf(((const float*)&wkB)[j], wrk[t + j].y, ak1);
      }
      const float q0 = siluf(aq0), q1 = siluf(aq1);
      const float k0 = siluf(ak0), k1 = siluf(ak1);
      qv[t] = make_float2(q0, q1);
      kv[t] = make_float2(k0, k1);
      sq[t] = fmaf(q1, q1, fmaf(q0, q0, sq[t]));
      sk[t] = fmaf(k1, k1, fmaf(k0, k0, sk[t]));
    }
  }
  // reduce sq,sk across 64 lanes, then across 4 waves
#pragma unroll
  for (int m = 1; m < 64; m <<= 1) {
#pragma unroll
    for (int t = 0; t < 8; ++t) {
      sq[t] += __shfl_xor(sq[t], m);
      sk[t] += __shfl_xor(sk[t], m);
    }
  }
  {
    const int w = tid >> 6, lane = tid & 63;
    if (lane == 0) {
#pragma unroll
      for (int t = 0; t < 8; ++t) { red[w][t] = sq[t]; red[w][8 + t] = sk[t]; }
    }
  }
  __syncthreads();
  float rnq[8], rnk[8];
#pragma unroll
  for (int t = 0; t < 8; ++t) {
    const float SQ = red[0][t] + red[1][t] + red[2][t] + red[3][t];
    const float SK = red[0][8 + t] + red[1][8 + t] + red[2][8 + t] + red[3][8 + t];
    rnq[t] = 1.f / fmaxf(sqrtf(SQ), 1e-12f);
    rnk[t] = 1.f / fmaxf(sqrtf(SK), 1e-12f);
  }
  {
    const int c0 = tid * 2;
#pragma unroll
    for (int t = 0; t < 8; ++t) {
      ushort2 oq, ok;
      oq.x = (unsigned short)bf16s(qv[t].x * rnq[t]);
      oq.y = (unsigned short)bf16s(qv[t].y * rnq[t]);
      ok.x = (unsigned short)bf16s(kv[t].x * rnk[t]);
      ok.y = (unsigned short)bf16s(kv[t].y * rnk[t]);
      *(ushort2*)((unsigned short*)qh + (size_t)(bl0 + t) * 512 + c0) = oq;
      *(ushort2*)((unsigned short*)kh + (size_t)(bl0 + t) * 512 + c0) = ok;
    }
  }
  // v: 4 consecutive channels per thread
  {
    const int cv = tid * 4;   // 0..1023
    const float4 wv0 = *(const float4*)(vcw + 4 * cv);
    const float4 wv1 = *(const float4*)(vcw + 4 * cv + 4);
    const float4 wv2 = *(const float4*)(vcw + 4 * cv + 8);
    const float4 wv3 = *(const float4*)(vcw + 4 * cv + 12);
    const float4 bv4 = *(const float4*)(vcb + cv);
    float4 wr[11];
#pragma unroll
    for (int r = 0; r < 11; ++r) {
      const int tt = t0 - 3 + r;
      if (tt >= 0) {
        const ushort4 u = *(const ushort4*)(Cu + (size_t)(bl0 - 3 + r) * NPROJ + 1024 + cv);
        wr[r] = make_float4(bfu2f(u.x), bfu2f(u.y), bfu2f(u.z), bfu2f(u.w));
      } else {
        wr[r] = make_float4(0.f, 0.f, 0.f, 0.f);
      }
    }
#pragma unroll
    for (int t = 0; t < 8; ++t) {
      float a0 = bv4.x, a1 = bv4.y, a2 = bv4.z, a3 = bv4.w;
#pragma unroll
      for (int j = 0; j < 4; ++j) {
        a0 = fmaf(((const float*)&wv0)[j], ((const float*)&wr[t + j])[0], a0);
        a1 = fmaf(((const float*)&wv1)[j], ((const float*)&wr[t + j])[1], a1);
        a2 = fmaf(((const float*)&wv2)[j], ((const float*)&wr[t + j])[2], a2);
        a3 = fmaf(((const float*)&wv3)[j], ((const float*)&wr[t + j])[3], a3);
      }
      ushort4 o;
      o.x = (unsigned short)bf16s(siluf(a0));
      o.y = (unsigned short)bf16s(siluf(a1));
      o.z = (unsigned short)bf16s(siluf(a2));
      o.w = (unsigned short)bf16s(siluf(a3));
      if (cv < 512) *(ushort4*)((unsigned short*)vm + (size_t)(bl0 + t) * 512 + cv)         = o;
      else          *(ushort4*)((unsigned short*)vg + (size_t)(bl0 + t) * 512 + (cv - 512)) = o;
    }
  }
  // alpha/beta from f32 side buffer: threads 0..63 cover 8 t x (4 al + 4 be)
  if (tid < 64) {
    const int t = tid >> 3;
    const int k = tid & 7;
    const float v = abf[(size_t)(bl0 + t) * 8 + k];
    if (k < 4) al[(size_t)(bl0 + t) * 4 + k]       = sigf(v);
    else       be[(size_t)(bl0 + t) * 4 + (k - 4)] = sigf(v);
  }
}

// ---------------- scan phase A (FUSED with transition), 512 threads ----------------
// 256 blocks = 32 chunks x 8 (b,h); 8 waves (2 waves/SIMD).
// Work split: G/Pq MFMA over 8 waves (t-band x s-half); substitution with TWO
// threads per column (A: rows 0-7 of each 16-block, B: rows 8-15, barrier
// handoff through the Xl spill); transition over 8 waves (row-band x col-qtr).
__global__ __launch_bounds__(512)
void scan_phaseA_kernel(const __hip_bfloat16* __restrict__ qh, const __hip_bfloat16* __restrict__ kh,
                        const __hip_bfloat16* __restrict__ vm, const float* __restrict__ al,
                        const float* __restrict__ be,
                        short* __restrict__ WTB, short* __restrict__ ZB,
                        short* __restrict__ PHB, float* __restrict__ GV,
                        short* __restrict__ TRB, float* __restrict__ BF)
{
  __shared__ char sm[136192];
  float* Xl = (float*)(sm);                             // [64][256] f32 (aliases KBl/QBl)
  __hip_bfloat16* KBl = (__hip_bfloat16*)(sm);          // [64][136]
  __hip_bfloat16* QBl = (__hip_bfloat16*)(sm + 17408);  // [64][136]
  float* Ll  = (float*)(sm + 65536);                    // [64][68]
  float* dv  = (float*)(sm + 82944);                    // [64]
  float* bv  = (float*)(sm + 83200);                    // [64]
  float* gbv = (float*)(sm + 83456);                    // [64]
  float* fvs = (float*)(sm + 83712);                    // [64]
  short* KTl  = (short*)(sm + 83968);                   // [128][68] bf16
  short* WTFl = (short*)(sm + 101376);                  // [128][68] bf16
  short* ZFl  = (short*)(sm + 118784);                  // [128][68] bf16

  const int cb = blockIdx.x;
  const int bh = cb & 7, c = cb >> 3;
  const int b = bh >> 2, h = bh & 3;
  const int tid = threadIdx.x;          // 0..511
  const int lane = tid & 63;
  const int w = tid >> 6;               // 0..7
  const int lr = lane & 15, lk = lane >> 4;
  const size_t rowbase = (size_t)(b * LQ + c * CT) * 512 + h * 128;

  // stage K,Q -> LDS bf16 (padded rows of 136); 2 reps of 512 threads
#pragma unroll
  for (int rep = 0; rep < 2; ++rep) {
    const int fid = tid + rep * 512;       // 0..1023
    const int r = fid >> 4;
    const int cg = (fid & 15) * 8;
    *(bf16x8*)(KBl + r * 136 + cg) = *(const bf16x8*)(kh + rowbase + (size_t)r * 512 + cg);
    *(bf16x8*)(QBl + r * 136 + cg) = *(const bf16x8*)(qh + rowbase + (size_t)r * 512 + cg);
  }
  // decay prefix (wave 0)
  if (w == 0) {
    float la = __logf(al[(size_t)(b * LQ + c * CT + lane) * 4 + h]);
    const float bb = be[(size_t)(b * LQ + c * CT + lane) * 4 + h];
#pragma unroll
    for (int off = 1; off < 64; off <<= 1) {
      const float tv = __shfl_up(la, off, 64);
      if (lane >= off) la += tv;
    }
    dv[lane] = la; bv[lane] = bb; gbv[lane] = bb * __expf(la);
    const float d63 = __shfl(la, 63, 64);
    fvs[lane] = __expf(d63 - la);
    GV[cb * 64 + lane] = __expf(la);
  }
  __syncthreads();

  // G = K K^T, Pq = Q K^T : wave w owns t-band (w&3) and s-half (w>>2)
  {
    const int tb = (w & 3) * 16;
    const int sh = (w >> 2) * 2;          // s-tile base (2 tiles per wave)
    f32x4 aG[2] = {}, aP[2] = {};
#pragma unroll
    for (int ks = 0; ks < 4; ++ks) {
      bf16x8 bk[2];
#pragma unroll
      for (int nt = 0; nt < 2; ++nt)
        bk[nt] = *(const bf16x8*)(KBl + ((sh + nt) * 16 + lr) * 136 + ks * 32 + lk * 8);
      const bf16x8 ak = *(const bf16x8*)(KBl + (tb + lr) * 136 + ks * 32 + lk * 8);
      const bf16x8 aq = *(const bf16x8*)(QBl + (tb + lr) * 136 + ks * 32 + lk * 8);
#pragma unroll
      for (int nt = 0; nt < 2; ++nt) {
        aG[nt] = MFMA16(ak, bk[nt], aG[nt]);
        aP[nt] = MFMA16(aq, bk[nt], aP[nt]);
      }
    }
#pragma unroll
    for (int nt = 0; nt < 2; ++nt)
#pragma unroll
      for (int jj = 0; jj < 4; ++jj) {
        const int t = tb + lk * 4 + jj;
        const int s = (sh + nt) * 16 + lr;
        const float eg = __expf(dv[t] - dv[s]);
        Ll[t * 68 + s] = (t > s) ? bv[t] * eg * aG[nt][jj] : 0.f;
        PHB[(size_t)cb * 4096 + t * 64 + s] = (s <= t) ? bf16s(eg * aP[nt][jj]) : (short)0;
      }
  }
  // KT (LDS) = K^T from staged KBl, BEFORE Xl overwrites it
  if (tid < 128) {
    const short* Kbs = (const short*)KBl;
#pragma unroll
    for (int s4 = 0; s4 < 16; ++s4) {
      s16x4 pk;
#pragma unroll
      for (int e = 0; e < 4; ++e)
        pk[e] = Kbs[(s4 * 4 + e) * 136 + tid];
      *(s16x4*)(KTl + tid * 68 + s4 * 4) = pk;
    }
  }
  __syncthreads();   // KBl/QBl dead from here -> Xl may overwrite

  // ---- blocked forward substitution: 2 threads per column ----
  const int j = tid & 255;
  const int half = tid >> 8;
  const int i0 = half * 8;
  const __hip_bfloat16* src = (j < 128) ? kh : vm;
  const __hip_bfloat16* xp = src + rowbase + (j & 127);
  float* XlC = Xl + j;                 // private column, stride 256 floats
  short* dstN = (j < 128) ? (WTB + (size_t)cb * 8192 + j)
                          : (ZB  + (size_t)cb * 8192 + (j - 128));
  short* dstT = (j < 128) ? (WTFl + j * 68)
                          : (ZFl  + (j - 128) * 68);

  for (int r = 0; r < 4; ++r) {
    float u[8];
#pragma unroll
    for (int i = 0; i < 8; ++i) {
      const int t = r * 16 + i0 + i;
      u[i] = __bfloat162float(xp[(size_t)t * 512]) * ((j < 128) ? gbv[t] : bv[t]);
    }
    for (int sc = 0; sc < r; ++sc) {
      float xs[16];
#pragma unroll
      for (int k = 0; k < 16; ++k) xs[k] = XlC[(sc * 16 + k) * 256];
#pragma unroll
      for (int i = 0; i < 8; ++i) {
        const float* lrow = Ll + (r * 16 + i0 + i) * 68 + sc * 16;
        const f32x4 l0 = *(const f32x4*)(lrow);
        const f32x4 l1 = *(const f32x4*)(lrow + 4);
        const f32x4 l2 = *(const f32x4*)(lrow + 8);
        const f32x4 l3 = *(const f32x4*)(lrow + 12);
        f32x4 acc = {};
        acc.x = fmaf(l0.x, xs[0],  acc.x); acc.y = fmaf(l0.y, xs[1],  acc.y);
        acc.z = fmaf(l0.z, xs[2],  acc.z); acc.w = fmaf(l0.w, xs[3],  acc.w);
        acc.x = fmaf(l1.x, xs[4],  acc.x); acc.y = fmaf(l1.y, xs[5],  acc.y);
        acc.z = fmaf(l1.z, xs[6],  acc.z); acc.w = fmaf(l1.w, xs[7],  acc.w);
        acc.x = fmaf(l2.x, xs[8],  acc.x); acc.y = fmaf(l2.y, xs[9],  acc.y);
        acc.z = fmaf(l2.z, xs[10], acc.z); acc.w = fmaf(l2.w, xs[11], acc.w);
        acc.x = fmaf(l3.x, xs[12], acc.x); acc.y = fmaf(l3.y, xs[13], acc.y);
        acc.z = fmaf(l3.z, xs[14], acc.z); acc.w = fmaf(l3.w, xs[15], acc.w);
        u[i] -= (acc.x + acc.y) + (acc.z + acc.w);
      }
    }
    if (half == 0) {
#pragma unroll
      for (int i = 1; i < 8; ++i) {
        const float* lrow = Ll + (r * 16 + i) * 68 + r * 16;
        f32x4 acc = {};
#pragma unroll
        for (int k4 = 0; k4 < 2; ++k4) {
          if (k4 * 4 < i) {
            const f32x4 lv = *(const f32x4*)(lrow + k4 * 4);
            acc.x = fmaf(lv.x, u[k4 * 4 + 0], acc.x);
            acc.y = fmaf(lv.y, u[k4 * 4 + 1], acc.y);
            acc.z = fmaf(lv.z, u[k4 * 4 + 2], acc.z);
            acc.w = fmaf(lv.w, u[k4 * 4 + 3], acc.w);
          }
        }
        u[i] -= (acc.x + acc.y) + (acc.z + acc.w);
      }
#pragma unroll
      for (int i = 0; i < 8; ++i) XlC[(r * 16 + i) * 256] = u[i];
#pragma unroll
      for (int i = 0; i < 8; ++i) dstN[(r * 16 + i) * 128] = bf16s(u[i]);
#pragma unroll
      for (int s4 = 0; s4 < 2; ++s4) {
        s16x4 p;
#pragma unroll
        for (int e = 0; e < 4; ++e)
          p[e] = bf16s(fvs[r * 16 + s4 * 4 + e] * u[s4 * 4 + e]);
        *(s16x4*)(dstT + r * 16 + s4 * 4) = p;
      }
    }
    __syncthreads();   // A-half spill visible
    if (half == 1) {
      float xa[8];
#pragma unroll
      for (int k = 0; k < 8; ++k) xa[k] = XlC[(r * 16 + k) * 256];
#pragma unroll
      for (int i = 0; i < 8; ++i) {
        const float* lrow = Ll + (r * 16 + 8 + i) * 68 + r * 16;
        const f32x4 l0 = *(const f32x4*)(lrow);
        const f32x4 l1 = *(const f32x4*)(lrow + 4);
        f32x4 acc = {};
        acc.x = fmaf(l0.x, xa[0], acc.x); acc.y = fmaf(l0.y, xa[1], acc.y);
        acc.z = fmaf(l0.z, xa[2], acc.z); acc.w = fmaf(l0.w, xa[3], acc.w);
        acc.x = fmaf(l1.x, xa[4], acc.x); acc.y = fmaf(l1.y, xa[5], acc.y);
        acc.z = fmaf(l1.z, xa[6], acc.z); acc.w = fmaf(l1.w, xa[7], acc.w);
        u[i] -= (acc.x + acc.y) + (acc.z + acc.w);
      }
#pragma unroll
      for (int i = 1; i < 8; ++i) {
        const float* lrow = Ll + (r * 16 + 8 + i) * 68 + r * 16 + 8;
        f32x4 acc = {};
#pragma unroll
        for (int k4 = 0; k4 < 2; ++k4) {
          if (k4 * 4 < i) {
            const f32x4 lv = *(const f32x4*)(lrow + k4 * 4);
            acc.x = fmaf(lv.x, u[k4 * 4 + 0], acc.x);
            acc.y = fmaf(lv.y, u[k4 * 4 + 1], acc.y);
            acc.z = fmaf(lv.z, u[k4 * 4 + 2], acc.z);
            acc.w = fmaf(lv.w, u[k4 * 4 + 3], acc.w);
          }
        }
        u[i] -= (acc.x + acc.y) + (acc.z + acc.w);
      }
#pragma unroll
      for (int i = 0; i < 8; ++i) XlC[(r * 16 + 8 + i) * 256] = u[i];
#pragma unroll
      for (int i = 0; i < 8; ++i) dstN[(r * 16 + 8 + i) * 128] = bf16s(u[i]);
#pragma unroll
      for (int s4 = 0; s4 < 2; ++s4) {
        s16x4 p;
#pragma unroll
        for (int e = 0; e < 4; ++e)
          p[e] = bf16s(fvs[r * 16 + 8 + s4 * 4 + e] * u[s4 * 4 + e]);
        *(s16x4*)(dstT + r * 16 + 8 + s4 * 4) = p;
      }
    }
    __syncthreads();   // block r fully solved
  }

  // ---- fused transition: 8 waves, wave w owns row-band (w&3) x col-quarter (w>>2)
  const float gc = __expf(dv[63]);
  const int rb = (w & 3) * 32;
  const int cq = (w >> 2) * 4;
  {
    f32x4 acc[2][4] = {};
#pragma unroll
    for (int ks = 0; ks < 2; ++ks) {
      const bf16x8 a0 = *(const bf16x8*)(KTl + (rb + lr) * 68 + ks * 32 + lk * 8);
      const bf16x8 a1 = *(const bf16x8*)(KTl + (rb + 16 + lr) * 68 + ks * 32 + lk * 8);
#pragma unroll
      for (int nt = 0; nt < 4; ++nt) {
        const bf16x8 bm = *(const bf16x8*)(WTFl + ((cq + nt) * 16 + lr) * 68 + ks * 32 + lk * 8);
        acc[0][nt] = MFMA16(a0, bm, acc[0][nt]);
        acc[1][nt] = MFMA16(a1, bm, acc[1][nt]);
      }
    }
#pragma unroll
    for (int mt = 0; mt < 2; ++mt)
#pragma unroll
      for (int nt = 0; nt < 4; ++nt)
#pragma unroll
        for (int jj = 0; jj < 4; ++jj) {
          const int jr = rb + mt * 16 + lk * 4 + jj;
          const int m  = (cq + nt) * 16 + lr;
          const float v = ((jr == m) ? gc : 0.f) - acc[mt][nt][jj];
          TRB[(size_t)cb * 16384 + jr * 128 + m] = bf16s(v);
        }
  }
  {
    f32x4 acc[2][4] = {};
#pragma unroll
    for (int ks = 0; ks < 2; ++ks) {
      const bf16x8 a0 = *(const bf16x8*)(ZFl + (rb + lr) * 68 + ks * 32 + lk * 8);
      const bf16x8 a1 = *(const bf16x8*)(ZFl + (rb + 16 + lr) * 68 + ks * 32 + lk * 8);
#pragma unroll
      for (int nt = 0; nt < 4; ++nt) {
        const bf16x8 bj = *(const bf16x8*)(KTl + ((cq + nt) * 16 + lr) * 68 + ks * 32 + lk * 8);
        acc[0][nt] = MFMA16(a0, bj, acc[0][nt]);
        acc[1][nt] = MFMA16(a1, bj, acc[1][nt]);
      }
    }
#pragma unroll
    for (int mt = 0; mt < 2; ++mt)
#pragma unroll
      for (int nt = 0; nt < 4; ++nt)
#pragma unroll
        for (int jj = 0; jj < 4; ++jj) {
          const int ir = rb + mt * 16 + lk * 4 + jj;
          const int jc = (cq + nt) * 16 + lr;
          BF[(size_t)cb * 16384 + ir * 128 + jc] = acc[mt][nt][jj];
        }
  }
}

// ---------------- scan state: serial chunk recurrence, S rows independent ----
#define L2_PREFETCH(BT, BA, CC) do {                                               \
  const int cbn_ = (CC) * 8 + bh;                                                  \
  _Pragma("unroll") for (int nt = 0; nt < 2; ++nt) {                               \
    _Pragma("unroll") for (int ks = 0; ks < 4; ++ks)                               \
      BT[nt][ks] = *(const bf16x8*)(TRB + (size_t)cbn_ * 16384 +                   \
                                    (w * 32 + nt * 16 + lr) * 128 + ks * 32 + lk * 8); \
    _Pragma("unroll") for (int jj = 0; jj < 4; ++jj)                               \
      BA[nt][jj] = BF[(size_t)cbn_ * 16384 + (r0 + lk * 4 + jj) * 128 +            \
                      w * 32 + nt * 16 + lr];                                      \
  }                                                                                \
} while (0)

#define L2_STEP(BT, BA, CC, PBT, PBA) do {                                         \
  const int cb_ = (CC) * 8 + bh;                                                   \
  { const int idx = tid * 8, r = idx >> 7, jc = idx & 127;                         \
    f32x4 s0 = *(const f32x4*)&Scur[r * 132 + jc];                                 \
    f32x4 s1 = *(const f32x4*)&Scur[r * 132 + jc + 4];                             \
    *(bf16x8*)(SALL + (size_t)cb_ * 16384 + (r0 + r) * 128 + jc) = pack8(s0, s1); }\
  bf16x8 af[4];                                                                    \
  _Pragma("unroll") for (int ks = 0; ks < 4; ++ks)                                 \
    af[ks] = pack8(*(const f32x4*)&Scur[lr * 132 + ks * 32 + lk * 8],              \
                   *(const f32x4*)&Scur[lr * 132 + ks * 32 + lk * 8 + 4]);         \
  if ((CC) < 31) L2_PREFETCH(PBT, PBA, (CC) + 1);                                  \
  f32x4 acc0 = {}, acc1 = {};                                                      \
  _Pragma("unroll") for (int ks = 0; ks < 4; ++ks) {                               \
    acc0 = MFMA16(af[ks], BT[0][ks], acc0);                                        \
    acc1 = MFMA16(af[ks], BT[1][ks], acc1);                                        \
  }                                                                                \
  _Pragma("unroll") for (int jj = 0; jj < 4; ++jj) {                               \
    Snxt[(lk * 4 + jj) * 132 + w * 32 + lr]      = acc0[jj] + BA[0][jj];           \
    Snxt[(lk * 4 + jj) * 132 + w * 32 + 16 + lr] = acc1[jj] + BA[1][jj];           \
  }                                                                                \
  __syncthreads();                                                                 \
  { float* t_ = Scur; Scur = Snxt; Snxt = t_; }                                    \
} while (0)

__global__ __launch_bounds__(256)
void scan_state_kernel(const short* __restrict__ TRB, const float* __restrict__ BF,
                       const float* __restrict__ st0, short* __restrict__ SALL,
                       float* __restrict__ stout)
{
  __shared__ float Sl[2 * 16 * 132];
  const int bid = blockIdx.x;            // 64
  const int bh = bid & 7, slab = bid >> 3;
  const int r0 = slab * 16;
  const int tid = threadIdx.x, lane = tid & 63, w = tid >> 6;
  const int lr = lane & 15, lk = lane >> 4;

  float* Scur = Sl;
  float* Snxt = Sl + 16 * 132;

  {
    const int idx = tid * 8, r = idx >> 7, jc = idx & 127;
    const float* sp = st0 + ((size_t)bh * 128 + r0 + r) * 128 + jc;
    *(f32x4*)&Scur[r * 132 + jc]     = *(const f32x4*)sp;
    *(f32x4*)&Scur[r * 132 + jc + 4] = *(const f32x4*)(sp + 4);
  }
  bf16x8 btA[2][4], btB[2][4];
  float  baA[2][4], baB[2][4];
  L2_PREFETCH(btA, baA, 0);
  __syncthreads();

  for (int c2 = 0; c2 < 16; ++c2) {
    L2_STEP(btA, baA, 2 * c2,     btB, baB);
    L2_STEP(btB, baB, 2 * c2 + 1, btA, baA);
  }

  {
    const int idx = tid * 8, r = idx >> 7, jc = idx & 127;
    float* sp = stout + ((size_t)bh * 128 + r0 + r) * 128 + jc;
    *(f32x4*)sp       = *(const f32x4*)&Scur[r * 132 + jc];
    *(f32x4*)(sp + 4) = *(const f32x4*)&Scur[r * 132 + jc + 4];
  }
}

// ---------------- scan output: fully parallel over chunks ----------------
__global__ __launch_bounds__(512)
void scan_output_kernel(const __hip_bfloat16* __restrict__ qh,
                        const short* __restrict__ WTB, const __hip_bfloat16* __restrict__ ZB,
                        const short* __restrict__ PHB, const float* __restrict__ GV,
                        const short* __restrict__ SALL, __hip_bfloat16* __restrict__ obuf)
{
  __shared__ short Ut[128 * 72];
  const int cb = blockIdx.x;
  const int bh = cb & 7, c = cb >> 3;
  const int b = bh >> 2, h = bh & 3;
  const int tid = threadIdx.x, lane = tid & 63, w = tid >> 6;   // w 0..7
  const int lr = lane & 15, lk = lane >> 4;
  const int r0 = (w & 3) * 16;

  f32x4 Y[8] = {};
#pragma unroll
  for (int ks = 0; ks < 4; ++ks) {
    bf16x8 af;
    if (w < 4) {
      af = *(const bf16x8*)(qh + ((size_t)(b * LQ + c * CT) + r0 + lr) * 512 + h * 128 + ks * 32 + lk * 8);
    } else {
      af = *(const bf16x8*)(WTB + (size_t)cb * 8192 + (r0 + lr) * 128 + ks * 32 + lk * 8);
    }
#pragma unroll
    for (int nt = 0; nt < 8; ++nt) {
      const bf16x8 bs = *(const bf16x8*)(SALL + (size_t)cb * 16384 + (nt * 16 + lr) * 128 + ks * 32 + lk * 8);
      Y[nt] = MFMA16(af, bs, Y[nt]);
    }
  }
  if (w >= 4) {   // U = Z - Y_low -> LDS (Ut[i][s])
#pragma unroll
    for (int nt = 0; nt < 8; ++nt) {
      const int i = nt * 16 + lr;
      s16x4 up;
#pragma unroll
      for (int jj = 0; jj < 4; ++jj) {
        const int s = r0 + lk * 4 + jj;
        const float z = __bfloat162float(ZB[(size_t)cb * 8192 + s * 128 + i]);
        up[jj] = bf16s(z - Y[nt][jj]);
      }
      *(s16x4*)&Ut[i * 72 + r0 + lk * 4] = up;
    }
  }
  __syncthreads();
  if (w < 4) {
    f32x4 P2[8] = {};
#pragma unroll
    for (int ks = 0; ks < 2; ++ks) {
      const bf16x8 ap = *(const bf16x8*)(PHB + (size_t)cb * 4096 + (r0 + lr) * 64 + ks * 32 + lk * 8);
#pragma unroll
      for (int nt = 0; nt < 8; ++nt) {
        const bf16x8 bu = *(const bf16x8*)&Ut[(nt * 16 + lr) * 72 + ks * 32 + lk * 8];
        P2[nt] = MFMA16(ap, bu, P2[nt]);
      }
    }
    float gvv[4];
#pragma unroll
    for (int jj = 0; jj < 4; ++jj) gvv[jj] = GV[cb * 64 + r0 + lk * 4 + jj];
#pragma unroll
    for (int nt = 0; nt < 8; ++nt) {
      const int i = nt * 16 + lr;
#pragma unroll
      for (int jj = 0; jj < 4; ++jj) {
        const int t = r0 + lk * 4 + jj;
        ((unsigned short*)obuf)[((size_t)(b * LQ + c * CT) + t) * 512 + h * 128 + i] =
            (unsigned short)bf16s(gvv[jj] * Y[nt][jj] + P2[nt][jj]);
      }
    }
  }
}

// ---------------- gate * silu(g), LayerNorm(512), cast bf16 ----------------
__global__ __launch_bounds__(256)
void gate_ln_kernel(const __hip_bfloat16* __restrict__ obuf, const __hip_bfloat16* __restrict__ vg,
                    const __hip_bfloat16* __restrict__ C, const float* __restrict__ lnw,
                    const float* __restrict__ lnb, __hip_bfloat16* __restrict__ lno)
{
  const int bl = blockIdx.x, tid = threadIdx.x;
  const int c0 = tid * 2;
  __shared__ float red[8];
  const ushort2 ovu = *(const ushort2*)((const unsigned short*)obuf + (size_t)bl * 512 + c0);
  const ushort2 gvu = *(const ushort2*)((const unsigned short*)vg + (size_t)bl * 512 + c0);
  const ushort2 ggu = *(const ushort2*)((const unsigned short*)C + (size_t)bl * NPROJ + 2048 + c0);
  const float v0 = bfu2f(ovu.x) * bfu2f(gvu.x) * siluf(bfu2f(ggu.x));
  const float v1 = bfu2f(ovu.y) * bfu2f(gvu.y) * siluf(bfu2f(ggu.y));
  float s = v0 + v1;
  float s2 = fmaf(v1, v1, v0 * v0);
  float2 pr = make_float2(s, s2);
#pragma unroll
  for (int m = 1; m < 64; m <<= 1) { pr.x += __shfl_xor(pr.x, m); pr.y += __shfl_xor(pr.y, m); }
  if ((tid & 63) == 0) { red[(tid >> 6) * 2] = pr.x; red[(tid >> 6) * 2 + 1] = pr.y; }
  __syncthreads();
  const float S  = red[0] + red[2] + red[4] + red[6];
  const float S2 = red[1] + red[3] + red[5] + red[7];
  const float mu  = S * (1.f / 512.f);
  const float var = S2 * (1.f / 512.f) - mu * mu;
  const float rs  = rsqrtf(var + 1e-5f);
  const float2 lw = *(const float2*)(lnw + c0);
  const float2 lb = *(const float2*)(lnb + c0);
  __hip_bfloat16 o[2] = {
    __float2bfloat16(fmaf((v0 - mu) * rs, lw.x, lb.x)),
    __float2bfloat16(fmaf((v1 - mu) * rs, lw.y, lb.y)) };
  *(ushort2*)((unsigned short*)lno + (size_t)bl * 512 + c0) = *(ushort2*)o;
}

extern "C" void kernel_launch(void* const* d_in, const int* in_sizes, int n_in,
                              void* d_out, int out_size, void* d_ws, size_t ws_size,
                              hipStream_t stream)
{
  (void)in_sizes; (void)n_in; (void)out_size; (void)ws_size;
  const float* x    = (const float*)d_in[0];
  const float* st0  = (const float*)d_in[1];
  const float* Wq   = (const float*)d_in[2];
  const float* Wk   = (const float*)d_in[3];
  const float* Wv   = (const float*)d_in[4];
  const float* Wa   = (const float*)d_in[5];
  const float* Wb   = (const float*)d_in[6];
  const float* Wg   = (const float*)d_in[7];
  const float* Wo   = (const float*)d_in[8];
  const float* qcw  = (const float*)d_in[9];
  const float* qcb  = (const float*)d_in[10];
  const float* kcw  = (const float*)d_in[11];
  const float* kcb  = (const float*)d_in[12];
  const float* vcw  = (const float*)d_in[13];
  const float* vcb  = (const float*)d_in[14];
  const float* lnw  = (const float*)d_in[15];
  const float* lnb  = (const float*)d_in[16];
  float* out = (float*)d_out;

  // workspace layout (bytes); high-water ~141.2 MB
  char* ws = (char*)d_ws;
  __hip_bfloat16* XB   = (__hip_bfloat16*)(ws + 0);            // 4096x1024 bf16 (dead after proj GEMM)
  __hip_bfloat16* LNO  = (__hip_bfloat16*)(ws + 0);            // 4096x512 bf16 (aliases XB 1st half)
  short*          WTB  = (short*)(ws + 4194304);               // [256][64][128] bf16 (aliases XB 2nd half)
  __hip_bfloat16* WCAT = (__hip_bfloat16*)(ws + 8388608);      // 2688x1024 bf16
  __hip_bfloat16* WOB  = (__hip_bfloat16*)(ws + 13893632);     // 1024x512  bf16
  __hip_bfloat16* CBUFH = (__hip_bfloat16*)(ws + 14942208);    // 4096x2688 bf16
  __hip_bfloat16* QH   = (__hip_bfloat16*)(ws + 58982400);     // 4096x512 bf16
  __hip_bfloat16* KH   = (__hip_bfloat16*)(ws + 67371008);     // 4096x512 bf16
  __hip_bfloat16* VM   = (__hip_bfloat16*)(ws + 75759616);     // 4096x512 bf16
  __hip_bfloat16* VG   = (__hip_bfloat16*)(ws + 84148224);     // 4096x512 bf16
  float* AL   = (float*)(ws + 92536832);                       // 4096x4
  float* BE   = (float*)(ws + 92602368);
  __hip_bfloat16* OBUF = (__hip_bfloat16*)(ws + 92667904);     // 4096x512 bf16 (written by scan_output)
  short* TRB  = (short*)(ws + 92667904);                       // [256][128][128] bf16 (aliases OBUF; dead before scan_output)
  short* PHB  = (short*)(ws + 105250816);                      // [256][64][64] bf16
  short* ZB   = (short*)(ws + 107347968);                      // [256][64][128] bf16
  float* GV   = (float*)(ws + 111542272);                      // [256][64]
  short* SALL = (short*)(ws + 115868672);                      // [256][128][128] bf16 chunk-start states
  float* ABF  = (float*)(ws + 124257280);                      // [4096][8] f32 alpha/beta logits
  float* BF   = (float*)(ws + 124388352);                      // [256][128][128] f32 (fresh region; no aliasing)

  cast_all_kernel<<<7296, 256, 0, stream>>>(x, Wo, Wq, Wk, Wv, Wg, Wa, Wb, XB, WOB, WCAT);

  gemm_bt_kernel<__hip_bfloat16><<<dim3(32, 21), 256, 0, stream>>>(
      XB, WCAT, CBUFH, BLQ, NPROJ, KPROJ, ABF, 2560);

  conv_act_kernel<<<512, 256, 0, stream>>>(CBUFH, ABF, qcw, qcb, kcw, kcb, vcw, vcb,
                                           QH, KH, VM, VG, AL, BE);

  scan_phaseA_kernel<<<256, 512, 0, stream>>>(QH, KH, VM, AL, BE,
                                              WTB, ZB, PHB, GV, TRB, BF);

  scan_state_kernel<<<64, 256, 0, stream>>>(TRB, BF, st0, SALL, out + 4194304);

  scan_output_kernel<<<256, 512, 0, stream>>>(QH, WTB, (const __hip_bfloat16*)ZB,
                                              PHB, GV, SALL, OBUF);

  gate_ln_kernel<<<BLQ, 256, 0, stream>>>(OBUF, VG, CBUFH, lnw, lnb, LNO);

  gemm_bt_kernel<float><<<dim3(32, 8), 256, 0, stream>>>(
      LNO, WOB, out, BLQ, DMQ, TOTQ, nullptr, 0);
}